// Round 19
// baseline (120.910 us; speedup 1.0000x reference)
//
#include <hip/hip_runtime.h>
#include <hip/hip_bf16.h>
#include <math.h>

#define B_ 4
#define N_ 2048
#define D_ 256
#define H_ 8
#define HD_ 32
#define F_ 1024
#define M_ (B_*N_)
#define EPS_ 1e-5f
#define VS2 136

typedef __attribute__((ext_vector_type(8))) short short8;
typedef __attribute__((ext_vector_type(4))) float f32x4;

// log2(e)/sqrt(32): folded into Q so softmax uses exp2 directly
#define QSC 0.2550565499f

#if __has_builtin(__builtin_amdgcn_exp2f)
__device__ inline float fexp2(float x) { return __builtin_amdgcn_exp2f(x); }
#else
__device__ inline float fexp2(float x) { float r; asm("v_exp_f32 %0, %1" : "=v"(r) : "v"(x)); return r; }
#endif
#if __has_builtin(__builtin_amdgcn_rcpf)
__device__ inline float frcp(float x) { return __builtin_amdgcn_rcpf(x); }
#else
__device__ inline float frcp(float x) { float r; asm("v_rcp_f32 %0, %1" : "=v"(r) : "v"(x)); return r; }
#endif

__device__ inline unsigned short f2bf(float f) {
    union { float f; unsigned u; } x; x.f = f;
    unsigned r = x.u + 0x7fff + ((x.u >> 16) & 1);
    return (unsigned short)(r >> 16);
}

__device__ inline unsigned pk_bf16(float a, float b) {
    union { __hip_bfloat162 h; unsigned u; } c;
    c.h = __float22bfloat162_rn(float2{a, b});
    return c.u;
}

// exact-GELU via Abramowitz-Stegun 7.1.26 erf (|eps| < 1.5e-7), raw v_exp/v_rcp
__device__ inline float gelu_f(float x) {
    float ax = fabsf(x);
    float z = ax * 0.70710678118654752f;
    float t = frcp(fmaf(0.3275911f, z, 1.0f));
    float e = fexp2(-z * z * 1.4426950408889634f);
    float poly = t * fmaf(t, fmaf(t, fmaf(t, fmaf(t, 1.061405429f, -1.453152027f),
                     1.421413741f), -0.284496736f), 0.254829592f);
    float erfv = 1.0f - poly * e;
    float s = (x < 0.f) ? -erfv : erfv;
    return 0.5f * x * (1.0f + s);
}

__device__ inline void async_copy16(const void* g, void* l) {
    __builtin_amdgcn_global_load_lds(
        (const __attribute__((address_space(1))) void*)g,
        (__attribute__((address_space(3))) void*)l, 16, 0, 0);
}

// ---------------- LayerNorm body: one wave per row, 4 rows/block -------------
__device__ inline void ln_rows(const float* __restrict__ x,
        const float* __restrict__ g, const float* __restrict__ be,
        unsigned short* __restrict__ out, int blk) {
    int w = threadIdx.x >> 6, lane = threadIdx.x & 63;
    int row = blk * 4 + w;
    float4 v = *(const float4*)&x[(size_t)row * D_ + lane * 4];
    float s  = v.x + v.y + v.z + v.w;
    float s2 = v.x * v.x + v.y * v.y + v.z * v.z + v.w * v.w;
    #pragma unroll
    for (int off = 1; off < 64; off <<= 1) {
        s  += __shfl_xor(s,  off, 64);
        s2 += __shfl_xor(s2, off, 64);
    }
    float mu  = s * (1.0f / D_);
    float var = s2 * (1.0f / D_) - mu * mu;
    float r = rsqrtf(var + EPS_);
    float4 gv = *(const float4*)&g[lane * 4];
    float4 bv = *(const float4*)&be[lane * 4];
    ushort4 u;
    u.x = f2bf((v.x - mu) * r * gv.x + bv.x);
    u.y = f2bf((v.y - mu) * r * gv.y + bv.y);
    u.z = f2bf((v.z - mu) * r * gv.z + bv.z);
    u.w = f2bf((v.w - mu) * r * gv.w + bv.w);
    *(ushort4*)&out[(size_t)row * D_ + lane * 4] = u;
}

__global__ __launch_bounds__(256) void ln_kernel(const float* __restrict__ x,
        const float* __restrict__ g, const float* __restrict__ be,
        unsigned short* __restrict__ out) {
    ln_rows(x, g, be, out, blockIdx.x);
}

// ---------------- prep: weight transpose | LN1 -------------------------------
__global__ __launch_bounds__(256) void prep_kernel(
        const float* __restrict__ wq, const float* __restrict__ wk,
        const float* __restrict__ wv, const float* __restrict__ wo,
        const float* __restrict__ w1, const float* __restrict__ w2,
        unsigned short* __restrict__ wqkvt, unsigned short* __restrict__ wot,
        unsigned short* __restrict__ w1t, unsigned short* __restrict__ w2t,
        const float* __restrict__ x, const float* __restrict__ g1,
        const float* __restrict__ be1, unsigned short* __restrict__ xn) {
    __shared__ float t[32][33];
    int id = blockIdx.x;
    if (id >= 768) {
        ln_rows(x, g1, be1, xn, id - 768);
        return;
    }
    const float* W; unsigned short* Wt; int K, Nc, n0, k0;
    if (id < 256) {
        int m = id >> 6, l = id & 63;
        K = 256; Nc = 256; n0 = (l & 7) * 32; k0 = (l >> 3) * 32;
        W  = m == 0 ? wq : (m == 1 ? wk : (m == 2 ? wv : wo));
        Wt = m == 0 ? wqkvt : (m == 1 ? wqkvt + 65536 : (m == 2 ? wqkvt + 131072 : wot));
    } else if (id < 512) {
        int l = id - 256; K = 256; Nc = 1024; n0 = (l & 31) * 32; k0 = (l >> 5) * 32;
        W = w1; Wt = w1t;
    } else {
        int l = id - 512; K = 1024; Nc = 256; n0 = (l & 7) * 32; k0 = (l >> 3) * 32;
        W = w2; Wt = w2t;
    }
    int tx = threadIdx.x & 31, ty = threadIdx.x >> 5;   // 32 x 8
    #pragma unroll
    for (int i = 0; i < 4; i++)
        t[ty + i * 8][tx] = W[(size_t)(k0 + ty + i * 8) * Nc + n0 + tx];
    __syncthreads();
    #pragma unroll
    for (int i = 0; i < 4; i++)
        Wt[(size_t)(n0 + ty + i * 8) * K + k0 + tx] = f2bf(t[tx][ty + i * 8]);
}

// ---------------- fused QKV GEMM + adj bit-packing ---------------------------
__global__ __launch_bounds__(256) void qkv_pack_kernel(
        const unsigned short* __restrict__ A,
        const unsigned short* __restrict__ Bt,
        const float* __restrict__ bq, const float* __restrict__ bk,
        const float* __restrict__ bv,
        unsigned short* __restrict__ q_out, unsigned short* __restrict__ k_out,
        unsigned short* __restrict__ v_out,
        const int* __restrict__ adj, unsigned short* __restrict__ mask16) {
    constexpr int MI = 4, NI = 2, BM = 128, BN = 64, K = 256, Nc = 768;
    __shared__ __align__(16) unsigned short Abuf[2][BM * 32];
    __shared__ __align__(16) unsigned short Bbuf[2][BN * 32];
    int bid = blockIdx.x;
    if (bid >= 768) {
        int g = (bid - 768) * 256 + threadIdx.x;   // u16 chunk index
        const int4* ap = (const int4*)adj + (size_t)g * 4;
        unsigned bits = 0;
        #pragma unroll
        for (int i = 0; i < 4; i++) {
            int4 v = ap[i];
            bits |= (v.x != 0 ? 1u : 0u) << (4 * i + 0);
            bits |= (v.y != 0 ? 1u : 0u) << (4 * i + 1);
            bits |= (v.z != 0 ? 1u : 0u) << (4 * i + 2);
            bits |= (v.w != 0 ? 1u : 0u) << (4 * i + 3);
        }
        mask16[g] = (unsigned short)bits;
        return;
    }
    int bx = bid % 12, by = bid / 12;
    int tid = threadIdx.x, w = tid >> 6, lane = tid & 63;
    int lr = lane & 15, lg = lane >> 4;
    int wy = w >> 1, wx = w & 1;
    int m0 = by * BM, n0 = bx * BN;
    f32x4 acc[MI][NI] = {};

    int srow = lane >> 2;
    int schunk = lane & 3;

    auto STAGE = [&](int k0, int bi) {
        #pragma unroll
        for (int i = 0; i < BM / 64; i++) {
            int ar = i * 64 + w * 16 + srow;
            int ac = schunk ^ ((ar >> 1) & 3);
            async_copy16(A + (size_t)(m0 + ar) * K + k0 + ac * 8,
                         &Abuf[bi][(i * 64 + w * 16) * 32]);
        }
        #pragma unroll
        for (int i = 0; i < BN / 64; i++) {
            int br = i * 64 + w * 16 + srow;
            int bc = schunk ^ ((br >> 1) & 3);
            async_copy16(Bt + (size_t)(n0 + br) * K + k0 + bc * 8,
                         &Bbuf[bi][(i * 64 + w * 16) * 32]);
        }
    };

    int nkt = K / 32;
    STAGE(0, 0);
    for (int kt = 0; kt < nkt; kt++) {
        __syncthreads();
        int cur = kt & 1;
        if (kt + 1 < nkt) STAGE((kt + 1) * 32, cur ^ 1);

        short8 af[MI], bf[NI];
        #pragma unroll
        for (int mi = 0; mi < MI; mi++) {
            int r = wy * (MI * 16) + mi * 16 + lr;
            int c = lg ^ ((r >> 1) & 3);
            af[mi] = *(const short8*)&Abuf[cur][r * 32 + c * 8];
        }
        #pragma unroll
        for (int ni = 0; ni < NI; ni++) {
            int r = wx * (NI * 16) + ni * 16 + lr;
            int c = lg ^ ((r >> 1) & 3);
            bf[ni] = *(const short8*)&Bbuf[cur][r * 32 + c * 8];
        }
        __builtin_amdgcn_s_setprio(1);
        #pragma unroll
        for (int mi = 0; mi < MI; mi++)
            #pragma unroll
            for (int ni = 0; ni < NI; ni++)
                acc[mi][ni] = __builtin_amdgcn_mfma_f32_16x16x32_bf16(
                        af[mi], bf[ni], acc[mi][ni], 0, 0, 0);
        __builtin_amdgcn_s_setprio(0);
    }

    #pragma unroll
    for (int mi = 0; mi < MI; mi++) {
        #pragma unroll
        for (int r = 0; r < 4; r++) {
            int grow = m0 + wy * (MI * 16) + mi * 16 + lg * 4 + r;
            #pragma unroll
            for (int ni = 0; ni < NI; ni++) {
                int gcol = n0 + wx * (NI * 16) + ni * 16 + lr;
                int which = gcol >> 8, nn = gcol & 255;
                const float* bp = which == 0 ? bq : (which == 1 ? bk : bv);
                float val = acc[mi][ni][r] + bp[nn];
                if (which == 0) val *= QSC;   // fold log2e/sqrt(HD) into Q
                unsigned short* dst = which == 0 ? q_out : (which == 1 ? k_out : v_out);
                int bb = grow >> 11, rr = grow & (N_ - 1);
                int hh = nn >> 5, dd = nn & 31;
                dst[((((size_t)bb * H_ + hh) * N_) + rr) * HD_ + dd] = f2bf(val);
            }
        }
    }
}

// ---------------- bf16 MFMA GEMM, double-buffered, 1 barrier / K-step -------
#define GM_RES  1   // f32 out, + bias + res
#define GM_GELU 2   // bf16 out, gelu(acc+bias)

template<int MODE, int MI, int NI>
__global__ __launch_bounds__(256) void gemm_mfma(
        const unsigned short* __restrict__ A,
        const unsigned short* __restrict__ Bt,
        const float* __restrict__ bias, const float* __restrict__ res,
        void* __restrict__ Cout, int M, int Nc, int K) {
    constexpr int BM = MI * 32, BN = NI * 32;
    __shared__ __align__(16) unsigned short Abuf[2][BM * 32];
    __shared__ __align__(16) unsigned short Bbuf[2][BN * 32];
    int tid = threadIdx.x, w = tid >> 6, lane = tid & 63;
    int lr = lane & 15, lg = lane >> 4;
    int wy = w >> 1, wx = w & 1;
    int m0 = blockIdx.y * BM, n0 = blockIdx.x * BN;
    f32x4 acc[MI][NI] = {};

    int srow = lane >> 2;
    int schunk = lane & 3;

    auto STAGE = [&](int k0, int bi) {
        #pragma unroll
        for (int i = 0; i < BM / 64; i++) {
            int ar = i * 64 + w * 16 + srow;
            int ac = schunk ^ ((ar >> 1) & 3);
            async_copy16(A + (size_t)(m0 + ar) * K + k0 + ac * 8,
                         &Abuf[bi][(i * 64 + w * 16) * 32]);
        }
        #pragma unroll
        for (int i = 0; i < BN / 64; i++) {
            int br = i * 64 + w * 16 + srow;
            int bc = schunk ^ ((br >> 1) & 3);
            async_copy16(Bt + (size_t)(n0 + br) * K + k0 + bc * 8,
                         &Bbuf[bi][(i * 64 + w * 16) * 32]);
        }
    };

    int nkt = K / 32;
    STAGE(0, 0);
    for (int kt = 0; kt < nkt; kt++) {
        __syncthreads();
        int cur = kt & 1;
        if (kt + 1 < nkt) STAGE((kt + 1) * 32, cur ^ 1);

        short8 af[MI], bf[NI];
        #pragma unroll
        for (int mi = 0; mi < MI; mi++) {
            int r = wy * (MI * 16) + mi * 16 + lr;
            int c = lg ^ ((r >> 1) & 3);
            af[mi] = *(const short8*)&Abuf[cur][r * 32 + c * 8];
        }
        #pragma unroll
        for (int ni = 0; ni < NI; ni++) {
            int r = wx * (NI * 16) + ni * 16 + lr;
            int c = lg ^ ((r >> 1) & 3);
            bf[ni] = *(const short8*)&Bbuf[cur][r * 32 + c * 8];
        }
        __builtin_amdgcn_s_setprio(1);
        #pragma unroll
        for (int mi = 0; mi < MI; mi++)
            #pragma unroll
            for (int ni = 0; ni < NI; ni++)
                acc[mi][ni] = __builtin_amdgcn_mfma_f32_16x16x32_bf16(
                        af[mi], bf[ni], acc[mi][ni], 0, 0, 0);
        __builtin_amdgcn_s_setprio(0);
    }

    #pragma unroll
    for (int mi = 0; mi < MI; mi++) {
        #pragma unroll
        for (int r = 0; r < 4; r++) {
            int grow = m0 + wy * (MI * 16) + mi * 16 + lg * 4 + r;
            #pragma unroll
            for (int ni = 0; ni < NI; ni++) {
                int gcol = n0 + wx * (NI * 16) + ni * 16 + lr;
                float val = acc[mi][ni][r];
                if (MODE == GM_RES) {
                    val += bias[gcol] + res[(size_t)grow * Nc + gcol];
                    ((float*)Cout)[(size_t)grow * Nc + gcol] = val;
                } else {
                    val = gelu_f(val + bias[gcol]);
                    ((unsigned short*)Cout)[(size_t)grow * Nc + gcol] = f2bf(val);
                }
            }
        }
    }
}

// ---------------- MFMA flash attention v16: 4 waves, 64 q-rows, KVBLK=128 ----
// Same per-tile math as the R16 winner; 4-wave blocks -> grid 1024 = 4
// independent blocks/CU (smaller barrier groups, cross-block overlap).
// All threads stage both K (global_load_lds) and sigma-packed V (reg->LDS).
__global__ __launch_bounds__(256) void attn_mfma14(
        const unsigned short* __restrict__ q, const unsigned short* __restrict__ k,
        const unsigned short* __restrict__ v, const unsigned long long* __restrict__ mask,
        unsigned short* __restrict__ ao) {
    __shared__ __align__(16) unsigned short Kb[2][128 * 32];  // K rows, chunk-swizzled
    __shared__ __align__(16) unsigned short Vt[2][32 * VS2];  // V^T [d][sigma128]
    int b = blockIdx.z, h = blockIdx.y;
    int q0 = blockIdx.x * 64;
    int tid = threadIdx.x, w = tid >> 6, lane = tid & 63;
    int lr = lane & 15, lg = lane >> 4;
    size_t bh = (size_t)(b * H_ + h);
    const unsigned short* qbp = q + bh * N_ * HD_;
    const unsigned short* kbp = k + bh * N_ * HD_;
    const unsigned short* vbp = v + bh * N_ * HD_;

    short8 qf = *(const short8*)&qbp[(size_t)(q0 + w * 16 + lr) * HD_ + lg * 8];
    const unsigned long long* mrow = mask + ((size_t)b * N_ + q0 + w * 16 + lr) * (N_ / 64);

    int swz = (lr & 3) ^ ((lr >> 2) & 3);          // K read chunk XOR
    // K staging: issue i stages rows i*64 + w*16 + sr (2 issues cover 128 rows)
    int sr = lane >> 2, sc = lane & 3;
    int ssw = (sr & 3) ^ ((sr >> 2) & 3);
    const unsigned short* ksrc = kbp + (size_t)(w * 16 + sr) * HD_ + (sc ^ ssw) * 8;
    // V staging: thread covers rows {2va,2va+1}, d slice [vd*8,+8)
    int va = tid & 63, vd = tid >> 6;
    const unsigned short* vsrc = vbp + (size_t)(2 * va) * HD_ + vd * 8;
    int p2 = 2 * va;                 // sigma128: keep kc bit, permute within 64
    int sig = (p2 & 64) | (p2 & 35) | ((p2 & 12) << 1) | ((p2 & 16) >> 2);

    short8 ones;
    #pragma unroll
    for (int i = 0; i < 8; i++) ones[i] = (short)0x3F80;   // bf16 1.0

    f32x4 acc0 = {}, acc1 = {}, acc_l = {};
    f32x4 zero = {};
    const int NT = N_ / 128;

    // ---- prologue: stage tile 0 into buffer 0 ----
    {
        async_copy16(ksrc,            &Kb[0][(w * 16) * 32]);
        async_copy16(ksrc + 64 * HD_, &Kb[0][(64 + w * 16) * 32]);
        short8 r0 = *(const short8*)vsrc;
        short8 r1 = *(const short8*)(vsrc + HD_);
        #pragma unroll
        for (int dd = 0; dd < 8; dd++) {
            unsigned pr = ((unsigned)(unsigned short)r1[dd] << 16) | (unsigned short)r0[dd];
            *(unsigned*)&Vt[0][(vd * 8 + dd) * VS2 + sig] = pr;
        }
    }
    unsigned long long mk0c = mrow[0], mk1c = mrow[1];
    unsigned long long mk0n = 0, mk1n = 0;
    short8 r0n = {}, r1n = {};

    for (int t = 0; t < NT; t++) {
        __syncthreads();                        // tile t staged (drains vmcnt+lgkm)
        int cur = t & 1;
        if (t + 1 < NT) {                       // prefetch t+1 (flies under compute)
            size_t koff = (size_t)(t + 1) * 128 * HD_;
            async_copy16(ksrc + koff,            &Kb[cur ^ 1][(w * 16) * 32]);
            async_copy16(ksrc + koff + 64 * HD_, &Kb[cur ^ 1][(64 + w * 16) * 32]);
            r0n = *(const short8*)(vsrc + koff);
            r1n = *(const short8*)(vsrc + koff + HD_);
            mk0n = mrow[2 * (t + 1)];
            mk1n = mrow[2 * (t + 1) + 1];
        }

        // S^T = K @ Q^T : lane (lr=q, lg) gets s for phys k = j*16 + lg*4 + r
        f32x4 s[8];
        __builtin_amdgcn_s_setprio(1);
        #pragma unroll
        for (int j = 0; j < 8; j++) {
            short8 kf = *(const short8*)&Kb[cur][(j * 16 + lr) * 32 + ((lg ^ swz) * 8)];
            s[j] = __builtin_amdgcn_mfma_f32_16x16x32_bf16(kf, qf, zero, 0, 0, 0);
        }
        __builtin_amdgcn_s_setprio(0);

        // max-free masked softmax numerator: select to -200 then raw v_exp (-> +0)
        unsigned mlo0 = (unsigned)(mk0c >> (lg * 4));
        unsigned mhi0 = (unsigned)(mk0c >> (lg * 4 + 32));
        unsigned mlo1 = (unsigned)(mk1c >> (lg * 4));
        unsigned mhi1 = (unsigned)(mk1c >> (lg * 4 + 32));
        #pragma unroll
        for (int j = 0; j < 8; j++) {
            int jj = j & 3;
            unsigned mw = (j < 4) ? ((jj & 2) ? mhi0 : mlo0)
                                  : ((jj & 2) ? mhi1 : mlo1);
            #pragma unroll
            for (int r = 0; r < 4; r++) {
                float sv = ((mw >> ((jj & 1) * 16 + r)) & 1) ? s[j][r] : -200.f;
                s[j][r] = fexp2(sv);
            }
        }

        // P is already the PV A-fragment (key-permuted V): pack in-register
        union u8 { short8 v8; unsigned u[4]; };
        u8 pf[4];
        #pragma unroll
        for (int kc = 0; kc < 4; kc++) {
            pf[kc].u[0] = pk_bf16(s[2 * kc][0], s[2 * kc][1]);
            pf[kc].u[1] = pk_bf16(s[2 * kc][2], s[2 * kc][3]);
            pf[kc].u[2] = pk_bf16(s[2 * kc + 1][0], s[2 * kc + 1][1]);
            pf[kc].u[3] = pk_bf16(s[2 * kc + 1][2], s[2 * kc + 1][3]);
        }

        __builtin_amdgcn_s_setprio(1);
        #pragma unroll
        for (int kc = 0; kc < 4; kc++) {
            short8 vfA = *(const short8*)&Vt[cur][lr * VS2 + kc * 32 + lg * 8];
            short8 vfB = *(const short8*)&Vt[cur][(lr + 16) * VS2 + kc * 32 + lg * 8];
            acc0  = __builtin_amdgcn_mfma_f32_16x16x32_bf16(pf[kc].v8, vfA, acc0, 0, 0, 0);
            acc1  = __builtin_amdgcn_mfma_f32_16x16x32_bf16(pf[kc].v8, vfB, acc1, 0, 0, 0);
            acc_l = __builtin_amdgcn_mfma_f32_16x16x32_bf16(pf[kc].v8, ones, acc_l, 0, 0, 0);
        }
        __builtin_amdgcn_s_setprio(0);

        if (t + 1 < NT) {                       // late V write (loads landed under compute)
            #pragma unroll
            for (int dd = 0; dd < 8; dd++) {
                unsigned pr = ((unsigned)(unsigned short)r1n[dd] << 16) | (unsigned short)r0n[dd];
                *(unsigned*)&Vt[cur ^ 1][(vd * 8 + dd) * VS2 + sig] = pr;
            }
        }
        mk0c = mk0n; mk1c = mk1n;
    }

    // acc_l[r] = l for q-row lg*4+r: already in output fragment layout
    #pragma unroll
    for (int r = 0; r < 4; r++) {
        float lv = acc_l[r];
        float ir = (lv > 0.f) ? frcp(lv) : 0.f;
        int row = q0 + w * 16 + lg * 4 + r;
        unsigned short* op = ao + ((size_t)(b * N_) + row) * D_ + h * HD_;
        op[lr]      = f2bf(acc0[r] * ir);
        op[lr + 16] = f2bf(acc1[r] * ir);
    }
}

// ---------------- Launch -----------------------------------------------------
extern "C" void kernel_launch(void* const* d_in, const int* in_sizes, int n_in,
                              void* d_out, int out_size, void* d_ws, size_t ws_size,
                              hipStream_t stream) {
    const float* x   = (const float*)d_in[0];
    const int*   adj = (const int*)d_in[1];
    const float* wq  = (const float*)d_in[2];
    const float* bq  = (const float*)d_in[3];
    const float* wk  = (const float*)d_in[4];
    const float* bk  = (const float*)d_in[5];
    const float* wv  = (const float*)d_in[6];
    const float* bv  = (const float*)d_in[7];
    const float* wo  = (const float*)d_in[8];
    const float* bo  = (const float*)d_in[9];
    const float* g1  = (const float*)d_in[10];
    const float* be1 = (const float*)d_in[11];
    const float* g2  = (const float*)d_in[12];
    const float* be2 = (const float*)d_in[13];
    const float* w1  = (const float*)d_in[14];
    const float* b1  = (const float*)d_in[15];
    const float* w2  = (const float*)d_in[16];
    const float* b2  = (const float*)d_in[17];
    float* out = (float*)d_out;
    char* base = (char*)d_ws;

    const size_t MB = (size_t)1 << 20;
    unsigned long long* mask = (unsigned long long*)(base);     // 2 MB
    unsigned short* xn     = (unsigned short*)(base + 2*MB);    // 4 MB
    unsigned short* qb     = (unsigned short*)(base + 6*MB);    // 4 MB
    unsigned short* kb     = (unsigned short*)(base + 10*MB);   // 4 MB
    unsigned short* vb     = (unsigned short*)(base + 14*MB);   // 4 MB
    unsigned short* ao     = (unsigned short*)(base + 18*MB);   // 4 MB
    float*          x2     = (float*)(base + 22*MB);            // 8 MB
    unsigned short* hn     = (unsigned short*)(base + 30*MB);   // 4 MB
    unsigned short* h1     = (unsigned short*)(base + 34*MB);   // 16 MB (FFN)
    unsigned short* wqkvt  = (unsigned short*)(base + 51*MB);   // 384 KB
    unsigned short* wot    = (unsigned short*)(base + 51*MB + 394240);   // 128 KB
    unsigned short* w1t    = (unsigned short*)(base + 52*MB);   // 512 KB
    unsigned short* w2t    = (unsigned short*)(base + 52*MB + 524288);   // 512 KB

    prep_kernel<<<768 + 2048, 256, 0, stream>>>(
        wq, wk, wv, wo, w1, w2, wqkvt, wot, w1t, w2t, x, g1, be1, xn);
    qkv_pack_kernel<<<768 + 4096, 256, 0, stream>>>(
        xn, wqkvt, bq, bk, bv, qb, kb, vb, adj, (unsigned short*)mask);
    attn_mfma14<<<dim3(N_ / 64, H_, B_), 256, 0, stream>>>(qb, kb, vb, mask, ao);
    gemm_mfma<GM_RES, 2, 2><<<dim3(4, 128), 256, 0, stream>>>(
        ao, wot, bo, x, x2, M_, 256, 256);
    ln_kernel<<<M_ / 4, 256, 0, stream>>>(x2, g2, be2, hn);
    gemm_mfma<GM_GELU, 2, 2><<<dim3(16, 128), 256, 0, stream>>>(
        hn, w1t, b1, nullptr, h1, M_, 1024, 256);
    gemm_mfma<GM_RES, 2, 2><<<dim3(4, 128), 256, 0, stream>>>(
        h1, w2t, b2, x2, out, M_, 256, 1024);
}

// Round 20
// 112.636 us; speedup vs baseline: 1.0735x; 1.0735x over previous
//
#include <hip/hip_runtime.h>
#include <hip/hip_bf16.h>
#include <math.h>

#define B_ 4
#define N_ 2048
#define D_ 256
#define H_ 8
#define HD_ 32
#define F_ 1024
#define M_ (B_*N_)
#define EPS_ 1e-5f
#define VS2 136

typedef __attribute__((ext_vector_type(8))) short short8;
typedef __attribute__((ext_vector_type(4))) float f32x4;

// log2(e)/sqrt(32): folded into Q so softmax uses exp2 directly
#define QSC 0.2550565499f

#if __has_builtin(__builtin_amdgcn_exp2f)
__device__ inline float fexp2(float x) { return __builtin_amdgcn_exp2f(x); }
#else
__device__ inline float fexp2(float x) { float r; asm("v_exp_f32 %0, %1" : "=v"(r) : "v"(x)); return r; }
#endif
#if __has_builtin(__builtin_amdgcn_rcpf)
__device__ inline float frcp(float x) { return __builtin_amdgcn_rcpf(x); }
#else
__device__ inline float frcp(float x) { float r; asm("v_rcp_f32 %0, %1" : "=v"(r) : "v"(x)); return r; }
#endif

__device__ inline unsigned short f2bf(float f) {
    union { float f; unsigned u; } x; x.f = f;
    unsigned r = x.u + 0x7fff + ((x.u >> 16) & 1);
    return (unsigned short)(r >> 16);
}

__device__ inline unsigned pk_bf16(float a, float b) {
    union { __hip_bfloat162 h; unsigned u; } c;
    c.h = __float22bfloat162_rn(float2{a, b});
    return c.u;
}

// exact-GELU via Abramowitz-Stegun 7.1.26 erf (|eps| < 1.5e-7), raw v_exp/v_rcp
__device__ inline float gelu_f(float x) {
    float ax = fabsf(x);
    float z = ax * 0.70710678118654752f;
    float t = frcp(fmaf(0.3275911f, z, 1.0f));
    float e = fexp2(-z * z * 1.4426950408889634f);
    float poly = t * fmaf(t, fmaf(t, fmaf(t, fmaf(t, 1.061405429f, -1.453152027f),
                     1.421413741f), -0.284496736f), 0.254829592f);
    float erfv = 1.0f - poly * e;
    float s = (x < 0.f) ? -erfv : erfv;
    return 0.5f * x * (1.0f + s);
}

__device__ inline void async_copy16(const void* g, void* l) {
    __builtin_amdgcn_global_load_lds(
        (const __attribute__((address_space(1))) void*)g,
        (__attribute__((address_space(3))) void*)l, 16, 0, 0);
}

// ---------------- LayerNorm body: one wave per row, 4 rows/block -------------
__device__ inline void ln_rows(const float* __restrict__ x,
        const float* __restrict__ g, const float* __restrict__ be,
        unsigned short* __restrict__ out, int blk) {
    int w = threadIdx.x >> 6, lane = threadIdx.x & 63;
    int row = blk * 4 + w;
    float4 v = *(const float4*)&x[(size_t)row * D_ + lane * 4];
    float s  = v.x + v.y + v.z + v.w;
    float s2 = v.x * v.x + v.y * v.y + v.z * v.z + v.w * v.w;
    #pragma unroll
    for (int off = 1; off < 64; off <<= 1) {
        s  += __shfl_xor(s,  off, 64);
        s2 += __shfl_xor(s2, off, 64);
    }
    float mu  = s * (1.0f / D_);
    float var = s2 * (1.0f / D_) - mu * mu;
    float r = rsqrtf(var + EPS_);
    float4 gv = *(const float4*)&g[lane * 4];
    float4 bv = *(const float4*)&be[lane * 4];
    ushort4 u;
    u.x = f2bf((v.x - mu) * r * gv.x + bv.x);
    u.y = f2bf((v.y - mu) * r * gv.y + bv.y);
    u.z = f2bf((v.z - mu) * r * gv.z + bv.z);
    u.w = f2bf((v.w - mu) * r * gv.w + bv.w);
    *(ushort4*)&out[(size_t)row * D_ + lane * 4] = u;
}

__global__ __launch_bounds__(256) void ln_kernel(const float* __restrict__ x,
        const float* __restrict__ g, const float* __restrict__ be,
        unsigned short* __restrict__ out) {
    ln_rows(x, g, be, out, blockIdx.x);
}

// ---------------- prep: weight transpose | LN1 -------------------------------
__global__ __launch_bounds__(256) void prep_kernel(
        const float* __restrict__ wq, const float* __restrict__ wk,
        const float* __restrict__ wv, const float* __restrict__ wo,
        const float* __restrict__ w1, const float* __restrict__ w2,
        unsigned short* __restrict__ wqkvt, unsigned short* __restrict__ wot,
        unsigned short* __restrict__ w1t, unsigned short* __restrict__ w2t,
        const float* __restrict__ x, const float* __restrict__ g1,
        const float* __restrict__ be1, unsigned short* __restrict__ xn) {
    __shared__ float t[32][33];
    int id = blockIdx.x;
    if (id >= 768) {
        ln_rows(x, g1, be1, xn, id - 768);
        return;
    }
    const float* W; unsigned short* Wt; int K, Nc, n0, k0;
    if (id < 256) {
        int m = id >> 6, l = id & 63;
        K = 256; Nc = 256; n0 = (l & 7) * 32; k0 = (l >> 3) * 32;
        W  = m == 0 ? wq : (m == 1 ? wk : (m == 2 ? wv : wo));
        Wt = m == 0 ? wqkvt : (m == 1 ? wqkvt + 65536 : (m == 2 ? wqkvt + 131072 : wot));
    } else if (id < 512) {
        int l = id - 256; K = 256; Nc = 1024; n0 = (l & 31) * 32; k0 = (l >> 5) * 32;
        W = w1; Wt = w1t;
    } else {
        int l = id - 512; K = 1024; Nc = 256; n0 = (l & 7) * 32; k0 = (l >> 3) * 32;
        W = w2; Wt = w2t;
    }
    int tx = threadIdx.x & 31, ty = threadIdx.x >> 5;   // 32 x 8
    #pragma unroll
    for (int i = 0; i < 4; i++)
        t[ty + i * 8][tx] = W[(size_t)(k0 + ty + i * 8) * Nc + n0 + tx];
    __syncthreads();
    #pragma unroll
    for (int i = 0; i < 4; i++)
        Wt[(size_t)(n0 + ty + i * 8) * K + k0 + tx] = f2bf(t[tx][ty + i * 8]);
}

// ---------------- fused QKV GEMM + adj bit-packing ---------------------------
__global__ __launch_bounds__(256) void qkv_pack_kernel(
        const unsigned short* __restrict__ A,
        const unsigned short* __restrict__ Bt,
        const float* __restrict__ bq, const float* __restrict__ bk,
        const float* __restrict__ bv,
        unsigned short* __restrict__ q_out, unsigned short* __restrict__ k_out,
        unsigned short* __restrict__ v_out,
        const int* __restrict__ adj, unsigned short* __restrict__ mask16) {
    constexpr int MI = 4, NI = 2, BM = 128, BN = 64, K = 256, Nc = 768;
    __shared__ __align__(16) unsigned short Abuf[2][BM * 32];
    __shared__ __align__(16) unsigned short Bbuf[2][BN * 32];
    int bid = blockIdx.x;
    if (bid >= 768) {
        int g = (bid - 768) * 256 + threadIdx.x;   // u16 chunk index
        const int4* ap = (const int4*)adj + (size_t)g * 4;
        unsigned bits = 0;
        #pragma unroll
        for (int i = 0; i < 4; i++) {
            int4 v = ap[i];
            bits |= (v.x != 0 ? 1u : 0u) << (4 * i + 0);
            bits |= (v.y != 0 ? 1u : 0u) << (4 * i + 1);
            bits |= (v.z != 0 ? 1u : 0u) << (4 * i + 2);
            bits |= (v.w != 0 ? 1u : 0u) << (4 * i + 3);
        }
        mask16[g] = (unsigned short)bits;
        return;
    }
    int bx = bid % 12, by = bid / 12;
    int tid = threadIdx.x, w = tid >> 6, lane = tid & 63;
    int lr = lane & 15, lg = lane >> 4;
    int wy = w >> 1, wx = w & 1;
    int m0 = by * BM, n0 = bx * BN;
    f32x4 acc[MI][NI] = {};

    int srow = lane >> 2;
    int schunk = lane & 3;

    auto STAGE = [&](int k0, int bi) {
        #pragma unroll
        for (int i = 0; i < BM / 64; i++) {
            int ar = i * 64 + w * 16 + srow;
            int ac = schunk ^ ((ar >> 1) & 3);
            async_copy16(A + (size_t)(m0 + ar) * K + k0 + ac * 8,
                         &Abuf[bi][(i * 64 + w * 16) * 32]);
        }
        #pragma unroll
        for (int i = 0; i < BN / 64; i++) {
            int br = i * 64 + w * 16 + srow;
            int bc = schunk ^ ((br >> 1) & 3);
            async_copy16(Bt + (size_t)(n0 + br) * K + k0 + bc * 8,
                         &Bbuf[bi][(i * 64 + w * 16) * 32]);
        }
    };

    int nkt = K / 32;
    STAGE(0, 0);
    for (int kt = 0; kt < nkt; kt++) {
        __syncthreads();
        int cur = kt & 1;
        if (kt + 1 < nkt) STAGE((kt + 1) * 32, cur ^ 1);

        short8 af[MI], bf[NI];
        #pragma unroll
        for (int mi = 0; mi < MI; mi++) {
            int r = wy * (MI * 16) + mi * 16 + lr;
            int c = lg ^ ((r >> 1) & 3);
            af[mi] = *(const short8*)&Abuf[cur][r * 32 + c * 8];
        }
        #pragma unroll
        for (int ni = 0; ni < NI; ni++) {
            int r = wx * (NI * 16) + ni * 16 + lr;
            int c = lg ^ ((r >> 1) & 3);
            bf[ni] = *(const short8*)&Bbuf[cur][r * 32 + c * 8];
        }
        __builtin_amdgcn_s_setprio(1);
        #pragma unroll
        for (int mi = 0; mi < MI; mi++)
            #pragma unroll
            for (int ni = 0; ni < NI; ni++)
                acc[mi][ni] = __builtin_amdgcn_mfma_f32_16x16x32_bf16(
                        af[mi], bf[ni], acc[mi][ni], 0, 0, 0);
        __builtin_amdgcn_s_setprio(0);
    }

    #pragma unroll
    for (int mi = 0; mi < MI; mi++) {
        #pragma unroll
        for (int r = 0; r < 4; r++) {
            int grow = m0 + wy * (MI * 16) + mi * 16 + lg * 4 + r;
            #pragma unroll
            for (int ni = 0; ni < NI; ni++) {
                int gcol = n0 + wx * (NI * 16) + ni * 16 + lr;
                int which = gcol >> 8, nn = gcol & 255;
                const float* bp = which == 0 ? bq : (which == 1 ? bk : bv);
                float val = acc[mi][ni][r] + bp[nn];
                if (which == 0) val *= QSC;   // fold log2e/sqrt(HD) into Q
                unsigned short* dst = which == 0 ? q_out : (which == 1 ? k_out : v_out);
                int bb = grow >> 11, rr = grow & (N_ - 1);
                int hh = nn >> 5, dd = nn & 31;
                dst[((((size_t)bb * H_ + hh) * N_) + rr) * HD_ + dd] = f2bf(val);
            }
        }
    }
}

// ---------------- bf16 MFMA GEMM, double-buffered, 1 barrier / K-step -------
#define GM_RES  1   // f32 out, + bias + res
#define GM_GELU 2   // bf16 out, gelu(acc+bias)

template<int MODE, int MI, int NI>
__global__ __launch_bounds__(256) void gemm_mfma(
        const unsigned short* __restrict__ A,
        const unsigned short* __restrict__ Bt,
        const float* __restrict__ bias, const float* __restrict__ res,
        void* __restrict__ Cout, int M, int Nc, int K) {
    constexpr int BM = MI * 32, BN = NI * 32;
    __shared__ __align__(16) unsigned short Abuf[2][BM * 32];
    __shared__ __align__(16) unsigned short Bbuf[2][BN * 32];
    int tid = threadIdx.x, w = tid >> 6, lane = tid & 63;
    int lr = lane & 15, lg = lane >> 4;
    int wy = w >> 1, wx = w & 1;
    int m0 = blockIdx.y * BM, n0 = blockIdx.x * BN;
    f32x4 acc[MI][NI] = {};

    int srow = lane >> 2;
    int schunk = lane & 3;

    auto STAGE = [&](int k0, int bi) {
        #pragma unroll
        for (int i = 0; i < BM / 64; i++) {
            int ar = i * 64 + w * 16 + srow;
            int ac = schunk ^ ((ar >> 1) & 3);
            async_copy16(A + (size_t)(m0 + ar) * K + k0 + ac * 8,
                         &Abuf[bi][(i * 64 + w * 16) * 32]);
        }
        #pragma unroll
        for (int i = 0; i < BN / 64; i++) {
            int br = i * 64 + w * 16 + srow;
            int bc = schunk ^ ((br >> 1) & 3);
            async_copy16(Bt + (size_t)(n0 + br) * K + k0 + bc * 8,
                         &Bbuf[bi][(i * 64 + w * 16) * 32]);
        }
    };

    int nkt = K / 32;
    STAGE(0, 0);
    for (int kt = 0; kt < nkt; kt++) {
        __syncthreads();
        int cur = kt & 1;
        if (kt + 1 < nkt) STAGE((kt + 1) * 32, cur ^ 1);

        short8 af[MI], bf[NI];
        #pragma unroll
        for (int mi = 0; mi < MI; mi++) {
            int r = wy * (MI * 16) + mi * 16 + lr;
            int c = lg ^ ((r >> 1) & 3);
            af[mi] = *(const short8*)&Abuf[cur][r * 32 + c * 8];
        }
        #pragma unroll
        for (int ni = 0; ni < NI; ni++) {
            int r = wx * (NI * 16) + ni * 16 + lr;
            int c = lg ^ ((r >> 1) & 3);
            bf[ni] = *(const short8*)&Bbuf[cur][r * 32 + c * 8];
        }
        __builtin_amdgcn_s_setprio(1);
        #pragma unroll
        for (int mi = 0; mi < MI; mi++)
            #pragma unroll
            for (int ni = 0; ni < NI; ni++)
                acc[mi][ni] = __builtin_amdgcn_mfma_f32_16x16x32_bf16(
                        af[mi], bf[ni], acc[mi][ni], 0, 0, 0);
        __builtin_amdgcn_s_setprio(0);
    }

    #pragma unroll
    for (int mi = 0; mi < MI; mi++) {
        #pragma unroll
        for (int r = 0; r < 4; r++) {
            int grow = m0 + wy * (MI * 16) + mi * 16 + lg * 4 + r;
            #pragma unroll
            for (int ni = 0; ni < NI; ni++) {
                int gcol = n0 + wx * (NI * 16) + ni * 16 + lr;
                float val = acc[mi][ni][r];
                if (MODE == GM_RES) {
                    val += bias[gcol] + res[(size_t)grow * Nc + gcol];
                    ((float*)Cout)[(size_t)grow * Nc + gcol] = val;
                } else {
                    val = gelu_f(val + bias[gcol]);
                    ((unsigned short*)Cout)[(size_t)grow * Nc + gcol] = f2bf(val);
                }
            }
        }
    }
}

// ---------------- MFMA flash attention: 8 waves, KVBLK=128 (R16 winner) ------
// + XCD-aware 1D block swizzle: 512 blocks, chunk of 64 consecutive logical
// blocks (= 4 full (b,h) K/V groups) per XCD -> K/V L2-resident per XCD.
__global__ __launch_bounds__(512) void attn_mfma12(
        const unsigned short* __restrict__ q, const unsigned short* __restrict__ k,
        const unsigned short* __restrict__ v, const unsigned long long* __restrict__ mask,
        unsigned short* __restrict__ ao) {
    __shared__ __align__(16) unsigned short Kb[2][128 * 32];  // K rows, chunk-swizzled
    __shared__ __align__(16) unsigned short Vt[2][32 * VS2];  // V^T [d][sigma128]
    // bijective XCD swizzle (512 % 8 == 0): xcd = flat & 7 gets logical chunk
    int swzb = (blockIdx.x & 7) * 64 + (blockIdx.x >> 3);
    int b = swzb >> 7, h = (swzb >> 4) & 7;
    int q0 = (swzb & 15) * 128;
    int tid = threadIdx.x, w = tid >> 6, lane = tid & 63;
    int lr = lane & 15, lg = lane >> 4;
    size_t bh = (size_t)(b * H_ + h);
    const unsigned short* qbp = q + bh * N_ * HD_;
    const unsigned short* kbp = k + bh * N_ * HD_;
    const unsigned short* vbp = v + bh * N_ * HD_;

    short8 qf = *(const short8*)&qbp[(size_t)(q0 + w * 16 + lr) * HD_ + lg * 8];
    const unsigned long long* mrow = mask + ((size_t)b * N_ + q0 + w * 16 + lr) * (N_ / 64);

    int swz = (lr & 3) ^ ((lr >> 2) & 3);          // K read chunk XOR
    // K staging (waves 0-3): wave w stages rows [w*32, w*32+32) (2 issues)
    int sr = lane >> 2, sc = lane & 3;
    int ssw = (sr & 3) ^ ((sr >> 2) & 3);
    const unsigned short* ksrc = kbp + (size_t)((w & 3) * 32 + sr) * HD_ + (sc ^ ssw) * 8;
    // V staging (waves 4-7): vtid in [0,256): rows {2va,2va+1}, d slice [vd*8,+8)
    int vtid = tid & 255;
    int va = vtid & 63, vd = vtid >> 6;
    const unsigned short* vsrc = vbp + (size_t)(2 * va) * HD_ + vd * 8;
    int p2 = 2 * va;                 // sigma128: keep kc bit, permute within 64
    int sig = (p2 & 64) | (p2 & 35) | ((p2 & 12) << 1) | ((p2 & 16) >> 2);

    short8 ones;
    #pragma unroll
    for (int i = 0; i < 8; i++) ones[i] = (short)0x3F80;   // bf16 1.0

    f32x4 acc0 = {}, acc1 = {}, acc_l = {};
    f32x4 zero = {};
    const int NT = N_ / 128;

    // ---- prologue: stage tile 0 into buffer 0 ----
    if (w < 4) {
        async_copy16(ksrc,            &Kb[0][((w & 3) * 32) * 32]);
        async_copy16(ksrc + 16 * HD_, &Kb[0][((w & 3) * 32 + 16) * 32]);
    } else {
        short8 r0 = *(const short8*)vsrc;
        short8 r1 = *(const short8*)(vsrc + HD_);
        #pragma unroll
        for (int dd = 0; dd < 8; dd++) {
            unsigned pr = ((unsigned)(unsigned short)r1[dd] << 16) | (unsigned short)r0[dd];
            *(unsigned*)&Vt[0][(vd * 8 + dd) * VS2 + sig] = pr;
        }
    }
    unsigned long long mk0c = mrow[0], mk1c = mrow[1];
    unsigned long long mk0n = 0, mk1n = 0;
    short8 r0n = {}, r1n = {};

    for (int t = 0; t < NT; t++) {
        __syncthreads();                        // tile t staged (drains vmcnt+lgkm)
        int cur = t & 1;
        if (t + 1 < NT) {                       // prefetch t+1 (flies under compute)
            size_t koff = (size_t)(t + 1) * 128 * HD_;
            if (w < 4) {
                async_copy16(ksrc + koff,            &Kb[cur ^ 1][((w & 3) * 32) * 32]);
                async_copy16(ksrc + koff + 16 * HD_, &Kb[cur ^ 1][((w & 3) * 32 + 16) * 32]);
            } else {
                r0n = *(const short8*)(vsrc + koff);
                r1n = *(const short8*)(vsrc + koff + HD_);
            }
            mk0n = mrow[2 * (t + 1)];
            mk1n = mrow[2 * (t + 1) + 1];
        }

        // S^T = K @ Q^T : lane (lr=q, lg) gets s for phys k = j*16 + lg*4 + r
        f32x4 s[8];
        __builtin_amdgcn_s_setprio(1);
        #pragma unroll
        for (int j = 0; j < 8; j++) {
            short8 kf = *(const short8*)&Kb[cur][(j * 16 + lr) * 32 + ((lg ^ swz) * 8)];
            s[j] = __builtin_amdgcn_mfma_f32_16x16x32_bf16(kf, qf, zero, 0, 0, 0);
        }
        __builtin_amdgcn_s_setprio(0);

        // max-free masked softmax numerator: select to -200 then raw v_exp (-> +0)
        unsigned mlo0 = (unsigned)(mk0c >> (lg * 4));
        unsigned mhi0 = (unsigned)(mk0c >> (lg * 4 + 32));
        unsigned mlo1 = (unsigned)(mk1c >> (lg * 4));
        unsigned mhi1 = (unsigned)(mk1c >> (lg * 4 + 32));
        #pragma unroll
        for (int j = 0; j < 8; j++) {
            int jj = j & 3;
            unsigned mw = (j < 4) ? ((jj & 2) ? mhi0 : mlo0)
                                  : ((jj & 2) ? mhi1 : mlo1);
            #pragma unroll
            for (int r = 0; r < 4; r++) {
                float sv = ((mw >> ((jj & 1) * 16 + r)) & 1) ? s[j][r] : -200.f;
                s[j][r] = fexp2(sv);
            }
        }

        // P is already the PV A-fragment (key-permuted V): pack in-register
        union u8 { short8 v8; unsigned u[4]; };
        u8 pf[4];
        #pragma unroll
        for (int kc = 0; kc < 4; kc++) {
            pf[kc].u[0] = pk_bf16(s[2 * kc][0], s[2 * kc][1]);
            pf[kc].u[1] = pk_bf16(s[2 * kc][2], s[2 * kc][3]);
            pf[kc].u[2] = pk_bf16(s[2 * kc + 1][0], s[2 * kc + 1][1]);
            pf[kc].u[3] = pk_bf16(s[2 * kc + 1][2], s[2 * kc + 1][3]);
        }

        __builtin_amdgcn_s_setprio(1);
        #pragma unroll
        for (int kc = 0; kc < 4; kc++) {
            short8 vfA = *(const short8*)&Vt[cur][lr * VS2 + kc * 32 + lg * 8];
            short8 vfB = *(const short8*)&Vt[cur][(lr + 16) * VS2 + kc * 32 + lg * 8];
            acc0  = __builtin_amdgcn_mfma_f32_16x16x32_bf16(pf[kc].v8, vfA, acc0, 0, 0, 0);
            acc1  = __builtin_amdgcn_mfma_f32_16x16x32_bf16(pf[kc].v8, vfB, acc1, 0, 0, 0);
            acc_l = __builtin_amdgcn_mfma_f32_16x16x32_bf16(pf[kc].v8, ones, acc_l, 0, 0, 0);
        }
        __builtin_amdgcn_s_setprio(0);

        if (w >= 4 && t + 1 < NT) {             // late V write (loads landed under compute)
            #pragma unroll
            for (int dd = 0; dd < 8; dd++) {
                unsigned pr = ((unsigned)(unsigned short)r1n[dd] << 16) | (unsigned short)r0n[dd];
                *(unsigned*)&Vt[cur ^ 1][(vd * 8 + dd) * VS2 + sig] = pr;
            }
        }
        mk0c = mk0n; mk1c = mk1n;
    }

    // acc_l[r] = l for q-row lg*4+r: already in output fragment layout
    #pragma unroll
    for (int r = 0; r < 4; r++) {
        float lv = acc_l[r];
        float ir = (lv > 0.f) ? frcp(lv) : 0.f;
        int row = q0 + w * 16 + lg * 4 + r;
        unsigned short* op = ao + ((size_t)(b * N_) + row) * D_ + h * HD_;
        op[lr]      = f2bf(acc0[r] * ir);
        op[lr + 16] = f2bf(acc1[r] * ir);
    }
}

// ---------------- Launch -----------------------------------------------------
extern "C" void kernel_launch(void* const* d_in, const int* in_sizes, int n_in,
                              void* d_out, int out_size, void* d_ws, size_t ws_size,
                              hipStream_t stream) {
    const float* x   = (const float*)d_in[0];
    const int*   adj = (const int*)d_in[1];
    const float* wq  = (const float*)d_in[2];
    const float* bq  = (const float*)d_in[3];
    const float* wk  = (const float*)d_in[4];
    const float* bk  = (const float*)d_in[5];
    const float* wv  = (const float*)d_in[6];
    const float* bv  = (const float*)d_in[7];
    const float* wo  = (const float*)d_in[8];
    const float* bo  = (const float*)d_in[9];
    const float* g1  = (const float*)d_in[10];
    const float* be1 = (const float*)d_in[11];
    const float* g2  = (const float*)d_in[12];
    const float* be2 = (const float*)d_in[13];
    const float* w1  = (const float*)d_in[14];
    const float* b1  = (const float*)d_in[15];
    const float* w2  = (const float*)d_in[16];
    const float* b2  = (const float*)d_in[17];
    float* out = (float*)d_out;
    char* base = (char*)d_ws;

    const size_t MB = (size_t)1 << 20;
    unsigned long long* mask = (unsigned long long*)(base);     // 2 MB
    unsigned short* xn     = (unsigned short*)(base + 2*MB);    // 4 MB
    unsigned short* qb     = (unsigned short*)(base + 6*MB);    // 4 MB
    unsigned short* kb     = (unsigned short*)(base + 10*MB);   // 4 MB
    unsigned short* vb     = (unsigned short*)(base + 14*MB);   // 4 MB
    unsigned short* ao     = (unsigned short*)(base + 18*MB);   // 4 MB
    float*          x2     = (float*)(base + 22*MB);            // 8 MB
    unsigned short* hn     = (unsigned short*)(base + 30*MB);   // 4 MB
    unsigned short* h1     = (unsigned short*)(base + 34*MB);   // 16 MB (FFN)
    unsigned short* wqkvt  = (unsigned short*)(base + 51*MB);   // 384 KB
    unsigned short* wot    = (unsigned short*)(base + 51*MB + 394240);   // 128 KB
    unsigned short* w1t    = (unsigned short*)(base + 52*MB);   // 512 KB
    unsigned short* w2t    = (unsigned short*)(base + 52*MB + 524288);   // 512 KB

    prep_kernel<<<768 + 2048, 256, 0, stream>>>(
        wq, wk, wv, wo, w1, w2, wqkvt, wot, w1t, w2t, x, g1, be1, xn);
    qkv_pack_kernel<<<768 + 4096, 256, 0, stream>>>(
        xn, wqkvt, bq, bk, bv, qb, kb, vb, adj, (unsigned short*)mask);
    attn_mfma12<<<512, 512, 0, stream>>>(qb, kb, vb, mask, ao);
    gemm_mfma<GM_RES, 2, 2><<<dim3(4, 128), 256, 0, stream>>>(
        ao, wot, bo, x, x2, M_, 256, 256);
    ln_kernel<<<M_ / 4, 256, 0, stream>>>(x2, g2, be2, hn);
    gemm_mfma<GM_GELU, 2, 2><<<dim3(16, 128), 256, 0, stream>>>(
        hn, w1t, b1, nullptr, h1, M_, 1024, 256);
    gemm_mfma<GM_RES, 2, 2><<<dim3(4, 128), 256, 0, stream>>>(
        h1, w2t, b2, x2, out, M_, 256, 1024);
}

// Round 21
// 111.107 us; speedup vs baseline: 1.0882x; 1.0138x over previous
//
#include <hip/hip_runtime.h>
#include <hip/hip_bf16.h>
#include <math.h>

#define B_ 4
#define N_ 2048
#define D_ 256
#define H_ 8
#define HD_ 32
#define F_ 1024
#define M_ (B_*N_)
#define EPS_ 1e-5f
#define VS2 136

typedef __attribute__((ext_vector_type(8))) short short8;
typedef __attribute__((ext_vector_type(4))) float f32x4;

// log2(e)/sqrt(32): folded into Q so softmax uses exp2 directly
#define QSC 0.2550565499f

#if __has_builtin(__builtin_amdgcn_exp2f)
__device__ inline float fexp2(float x) { return __builtin_amdgcn_exp2f(x); }
#else
__device__ inline float fexp2(float x) { float r; asm("v_exp_f32 %0, %1" : "=v"(r) : "v"(x)); return r; }
#endif
#if __has_builtin(__builtin_amdgcn_rcpf)
__device__ inline float frcp(float x) { return __builtin_amdgcn_rcpf(x); }
#else
__device__ inline float frcp(float x) { float r; asm("v_rcp_f32 %0, %1" : "=v"(r) : "v"(x)); return r; }
#endif

__device__ inline unsigned short f2bf(float f) {
    union { float f; unsigned u; } x; x.f = f;
    unsigned r = x.u + 0x7fff + ((x.u >> 16) & 1);
    return (unsigned short)(r >> 16);
}

__device__ inline float bf2f(unsigned short u) {
    union { unsigned u; float f; } c; c.u = (unsigned)u << 16;
    return c.f;
}

__device__ inline unsigned pk_bf16(float a, float b) {
    union { __hip_bfloat162 h; unsigned u; } c;
    c.h = __float22bfloat162_rn(float2{a, b});
    return c.u;
}

// exact-GELU via Abramowitz-Stegun 7.1.26 erf (|eps| < 1.5e-7), raw v_exp/v_rcp
__device__ inline float gelu_f(float x) {
    float ax = fabsf(x);
    float z = ax * 0.70710678118654752f;
    float t = frcp(fmaf(0.3275911f, z, 1.0f));
    float e = fexp2(-z * z * 1.4426950408889634f);
    float poly = t * fmaf(t, fmaf(t, fmaf(t, fmaf(t, 1.061405429f, -1.453152027f),
                     1.421413741f), -0.284496736f), 0.254829592f);
    float erfv = 1.0f - poly * e;
    float s = (x < 0.f) ? -erfv : erfv;
    return 0.5f * x * (1.0f + s);
}

__device__ inline void async_copy16(const void* g, void* l) {
    __builtin_amdgcn_global_load_lds(
        (const __attribute__((address_space(1))) void*)g,
        (__attribute__((address_space(3))) void*)l, 16, 0, 0);
}

// ---------------- LayerNorm (f32 in): one wave/row; also emits bf16(x) ------
__device__ inline void ln_rows_f32(const float* __restrict__ x,
        const float* __restrict__ g, const float* __restrict__ be,
        unsigned short* __restrict__ out, unsigned short* __restrict__ xbf,
        int blk) {
    int w = threadIdx.x >> 6, lane = threadIdx.x & 63;
    int row = blk * 4 + w;
    float4 v = *(const float4*)&x[(size_t)row * D_ + lane * 4];
    float s  = v.x + v.y + v.z + v.w;
    float s2 = v.x * v.x + v.y * v.y + v.z * v.z + v.w * v.w;
    #pragma unroll
    for (int off = 1; off < 64; off <<= 1) {
        s  += __shfl_xor(s,  off, 64);
        s2 += __shfl_xor(s2, off, 64);
    }
    float mu  = s * (1.0f / D_);
    float var = s2 * (1.0f / D_) - mu * mu;
    float r = rsqrtf(var + EPS_);
    float4 gv = *(const float4*)&g[lane * 4];
    float4 bv = *(const float4*)&be[lane * 4];
    ushort4 u;
    u.x = f2bf((v.x - mu) * r * gv.x + bv.x);
    u.y = f2bf((v.y - mu) * r * gv.y + bv.y);
    u.z = f2bf((v.z - mu) * r * gv.z + bv.z);
    u.w = f2bf((v.w - mu) * r * gv.w + bv.w);
    *(ushort4*)&out[(size_t)row * D_ + lane * 4] = u;
    if (xbf) {
        ushort4 xb;
        xb.x = f2bf(v.x); xb.y = f2bf(v.y); xb.z = f2bf(v.z); xb.w = f2bf(v.w);
        *(ushort4*)&xbf[(size_t)row * D_ + lane * 4] = xb;
    }
}

// ---------------- LayerNorm (bf16 in), bf16 out ------------------------------
__global__ __launch_bounds__(256) void ln_bf_kernel(
        const unsigned short* __restrict__ xb, const float* __restrict__ g,
        const float* __restrict__ be, unsigned short* __restrict__ out) {
    int w = threadIdx.x >> 6, lane = threadIdx.x & 63;
    int row = blockIdx.x * 4 + w;
    ushort4 uv = *(const ushort4*)&xb[(size_t)row * D_ + lane * 4];
    float v0 = bf2f(uv.x), v1 = bf2f(uv.y), v2 = bf2f(uv.z), v3 = bf2f(uv.w);
    float s  = v0 + v1 + v2 + v3;
    float s2 = v0 * v0 + v1 * v1 + v2 * v2 + v3 * v3;
    #pragma unroll
    for (int off = 1; off < 64; off <<= 1) {
        s  += __shfl_xor(s,  off, 64);
        s2 += __shfl_xor(s2, off, 64);
    }
    float mu  = s * (1.0f / D_);
    float var = s2 * (1.0f / D_) - mu * mu;
    float r = rsqrtf(var + EPS_);
    float4 gv = *(const float4*)&g[lane * 4];
    float4 bv = *(const float4*)&be[lane * 4];
    ushort4 u;
    u.x = f2bf((v0 - mu) * r * gv.x + bv.x);
    u.y = f2bf((v1 - mu) * r * gv.y + bv.y);
    u.z = f2bf((v2 - mu) * r * gv.z + bv.z);
    u.w = f2bf((v3 - mu) * r * gv.w + bv.w);
    *(ushort4*)&out[(size_t)row * D_ + lane * 4] = u;
}

// ---------------- prep: weight transpose | LN1 (+bf16 x copy) ----------------
__global__ __launch_bounds__(256) void prep_kernel(
        const float* __restrict__ wq, const float* __restrict__ wk,
        const float* __restrict__ wv, const float* __restrict__ wo,
        const float* __restrict__ w1, const float* __restrict__ w2,
        unsigned short* __restrict__ wqkvt, unsigned short* __restrict__ wot,
        unsigned short* __restrict__ w1t, unsigned short* __restrict__ w2t,
        const float* __restrict__ x, const float* __restrict__ g1,
        const float* __restrict__ be1, unsigned short* __restrict__ xn,
        unsigned short* __restrict__ xbf) {
    __shared__ float t[32][33];
    int id = blockIdx.x;
    if (id >= 768) {
        ln_rows_f32(x, g1, be1, xn, xbf, id - 768);
        return;
    }
    const float* W; unsigned short* Wt; int K, Nc, n0, k0;
    if (id < 256) {
        int m = id >> 6, l = id & 63;
        K = 256; Nc = 256; n0 = (l & 7) * 32; k0 = (l >> 3) * 32;
        W  = m == 0 ? wq : (m == 1 ? wk : (m == 2 ? wv : wo));
        Wt = m == 0 ? wqkvt : (m == 1 ? wqkvt + 65536 : (m == 2 ? wqkvt + 131072 : wot));
    } else if (id < 512) {
        int l = id - 256; K = 256; Nc = 1024; n0 = (l & 31) * 32; k0 = (l >> 5) * 32;
        W = w1; Wt = w1t;
    } else {
        int l = id - 512; K = 1024; Nc = 256; n0 = (l & 7) * 32; k0 = (l >> 3) * 32;
        W = w2; Wt = w2t;
    }
    int tx = threadIdx.x & 31, ty = threadIdx.x >> 5;   // 32 x 8
    #pragma unroll
    for (int i = 0; i < 4; i++)
        t[ty + i * 8][tx] = W[(size_t)(k0 + ty + i * 8) * Nc + n0 + tx];
    __syncthreads();
    #pragma unroll
    for (int i = 0; i < 4; i++)
        Wt[(size_t)(n0 + ty + i * 8) * K + k0 + tx] = f2bf(t[tx][ty + i * 8]);
}

// ---------------- fused QKV GEMM + adj bit-packing ---------------------------
__global__ __launch_bounds__(256) void qkv_pack_kernel(
        const unsigned short* __restrict__ A,
        const unsigned short* __restrict__ Bt,
        const float* __restrict__ bq, const float* __restrict__ bk,
        const float* __restrict__ bv,
        unsigned short* __restrict__ q_out, unsigned short* __restrict__ k_out,
        unsigned short* __restrict__ v_out,
        const int* __restrict__ adj, unsigned short* __restrict__ mask16) {
    constexpr int MI = 4, NI = 2, BM = 128, BN = 64, K = 256, Nc = 768;
    __shared__ __align__(16) unsigned short Abuf[2][BM * 32];
    __shared__ __align__(16) unsigned short Bbuf[2][BN * 32];
    int bid = blockIdx.x;
    if (bid >= 768) {
        int g = (bid - 768) * 256 + threadIdx.x;   // u16 chunk index
        const int4* ap = (const int4*)adj + (size_t)g * 4;
        unsigned bits = 0;
        #pragma unroll
        for (int i = 0; i < 4; i++) {
            int4 v = ap[i];
            bits |= (v.x != 0 ? 1u : 0u) << (4 * i + 0);
            bits |= (v.y != 0 ? 1u : 0u) << (4 * i + 1);
            bits |= (v.z != 0 ? 1u : 0u) << (4 * i + 2);
            bits |= (v.w != 0 ? 1u : 0u) << (4 * i + 3);
        }
        mask16[g] = (unsigned short)bits;
        return;
    }
    int bx = bid % 12, by = bid / 12;
    int tid = threadIdx.x, w = tid >> 6, lane = tid & 63;
    int lr = lane & 15, lg = lane >> 4;
    int wy = w >> 1, wx = w & 1;
    int m0 = by * BM, n0 = bx * BN;
    f32x4 acc[MI][NI] = {};

    int srow = lane >> 2;
    int schunk = lane & 3;

    auto STAGE = [&](int k0, int bi) {
        #pragma unroll
        for (int i = 0; i < BM / 64; i++) {
            int ar = i * 64 + w * 16 + srow;
            int ac = schunk ^ ((ar >> 1) & 3);
            async_copy16(A + (size_t)(m0 + ar) * K + k0 + ac * 8,
                         &Abuf[bi][(i * 64 + w * 16) * 32]);
        }
        #pragma unroll
        for (int i = 0; i < BN / 64; i++) {
            int br = i * 64 + w * 16 + srow;
            int bc = schunk ^ ((br >> 1) & 3);
            async_copy16(Bt + (size_t)(n0 + br) * K + k0 + bc * 8,
                         &Bbuf[bi][(i * 64 + w * 16) * 32]);
        }
    };

    int nkt = K / 32;
    STAGE(0, 0);
    for (int kt = 0; kt < nkt; kt++) {
        __syncthreads();
        int cur = kt & 1;
        if (kt + 1 < nkt) STAGE((kt + 1) * 32, cur ^ 1);

        short8 af[MI], bf[NI];
        #pragma unroll
        for (int mi = 0; mi < MI; mi++) {
            int r = wy * (MI * 16) + mi * 16 + lr;
            int c = lg ^ ((r >> 1) & 3);
            af[mi] = *(const short8*)&Abuf[cur][r * 32 + c * 8];
        }
        #pragma unroll
        for (int ni = 0; ni < NI; ni++) {
            int r = wx * (NI * 16) + ni * 16 + lr;
            int c = lg ^ ((r >> 1) & 3);
            bf[ni] = *(const short8*)&Bbuf[cur][r * 32 + c * 8];
        }
        __builtin_amdgcn_s_setprio(1);
        #pragma unroll
        for (int mi = 0; mi < MI; mi++)
            #pragma unroll
            for (int ni = 0; ni < NI; ni++)
                acc[mi][ni] = __builtin_amdgcn_mfma_f32_16x16x32_bf16(
                        af[mi], bf[ni], acc[mi][ni], 0, 0, 0);
        __builtin_amdgcn_s_setprio(0);
    }

    #pragma unroll
    for (int mi = 0; mi < MI; mi++) {
        #pragma unroll
        for (int r = 0; r < 4; r++) {
            int grow = m0 + wy * (MI * 16) + mi * 16 + lg * 4 + r;
            #pragma unroll
            for (int ni = 0; ni < NI; ni++) {
                int gcol = n0 + wx * (NI * 16) + ni * 16 + lr;
                int which = gcol >> 8, nn = gcol & 255;
                const float* bp = which == 0 ? bq : (which == 1 ? bk : bv);
                float val = acc[mi][ni][r] + bp[nn];
                if (which == 0) val *= QSC;   // fold log2e/sqrt(HD) into Q
                unsigned short* dst = which == 0 ? q_out : (which == 1 ? k_out : v_out);
                int bb = grow >> 11, rr = grow & (N_ - 1);
                int hh = nn >> 5, dd = nn & 31;
                dst[((((size_t)bb * H_ + hh) * N_) + rr) * HD_ + dd] = f2bf(val);
            }
        }
    }
}

// ---------------- bf16 MFMA GEMM, double-buffered, 1 barrier / K-step -------
// MODE 1: bf16 res, bf16 out (O-proj).  MODE 2: gelu, bf16 out (FFN1).
// MODE 3: bf16 res, f32 out (FFN2 -> final output).
template<int MODE, int MI, int NI>
__global__ __launch_bounds__(256) void gemm_mfma(
        const unsigned short* __restrict__ A,
        const unsigned short* __restrict__ Bt,
        const float* __restrict__ bias, const unsigned short* __restrict__ res,
        void* __restrict__ Cout, int M, int Nc, int K) {
    constexpr int BM = MI * 32, BN = NI * 32;
    __shared__ __align__(16) unsigned short Abuf[2][BM * 32];
    __shared__ __align__(16) unsigned short Bbuf[2][BN * 32];
    int tid = threadIdx.x, w = tid >> 6, lane = tid & 63;
    int lr = lane & 15, lg = lane >> 4;
    int wy = w >> 1, wx = w & 1;
    int m0 = blockIdx.y * BM, n0 = blockIdx.x * BN;
    f32x4 acc[MI][NI] = {};

    int srow = lane >> 2;
    int schunk = lane & 3;

    auto STAGE = [&](int k0, int bi) {
        #pragma unroll
        for (int i = 0; i < BM / 64; i++) {
            int ar = i * 64 + w * 16 + srow;
            int ac = schunk ^ ((ar >> 1) & 3);
            async_copy16(A + (size_t)(m0 + ar) * K + k0 + ac * 8,
                         &Abuf[bi][(i * 64 + w * 16) * 32]);
        }
        #pragma unroll
        for (int i = 0; i < BN / 64; i++) {
            int br = i * 64 + w * 16 + srow;
            int bc = schunk ^ ((br >> 1) & 3);
            async_copy16(Bt + (size_t)(n0 + br) * K + k0 + bc * 8,
                         &Bbuf[bi][(i * 64 + w * 16) * 32]);
        }
    };

    int nkt = K / 32;
    STAGE(0, 0);
    for (int kt = 0; kt < nkt; kt++) {
        __syncthreads();
        int cur = kt & 1;
        if (kt + 1 < nkt) STAGE((kt + 1) * 32, cur ^ 1);

        short8 af[MI], bf[NI];
        #pragma unroll
        for (int mi = 0; mi < MI; mi++) {
            int r = wy * (MI * 16) + mi * 16 + lr;
            int c = lg ^ ((r >> 1) & 3);
            af[mi] = *(const short8*)&Abuf[cur][r * 32 + c * 8];
        }
        #pragma unroll
        for (int ni = 0; ni < NI; ni++) {
            int r = wx * (NI * 16) + ni * 16 + lr;
            int c = lg ^ ((r >> 1) & 3);
            bf[ni] = *(const short8*)&Bbuf[cur][r * 32 + c * 8];
        }
        __builtin_amdgcn_s_setprio(1);
        #pragma unroll
        for (int mi = 0; mi < MI; mi++)
            #pragma unroll
            for (int ni = 0; ni < NI; ni++)
                acc[mi][ni] = __builtin_amdgcn_mfma_f32_16x16x32_bf16(
                        af[mi], bf[ni], acc[mi][ni], 0, 0, 0);
        __builtin_amdgcn_s_setprio(0);
    }

    #pragma unroll
    for (int mi = 0; mi < MI; mi++) {
        #pragma unroll
        for (int r = 0; r < 4; r++) {
            int grow = m0 + wy * (MI * 16) + mi * 16 + lg * 4 + r;
            #pragma unroll
            for (int ni = 0; ni < NI; ni++) {
                int gcol = n0 + wx * (NI * 16) + ni * 16 + lr;
                float val = acc[mi][ni][r] + bias[gcol];
                if (MODE == 2) {
                    val = gelu_f(val);
                    ((unsigned short*)Cout)[(size_t)grow * Nc + gcol] = f2bf(val);
                } else {
                    val += bf2f(res[(size_t)grow * Nc + gcol]);
                    if (MODE == 1)
                        ((unsigned short*)Cout)[(size_t)grow * Nc + gcol] = f2bf(val);
                    else
                        ((float*)Cout)[(size_t)grow * Nc + gcol] = val;
                }
            }
        }
    }
}

// ---------------- MFMA flash attention: 8 waves, KVBLK=128 + XCD swizzle -----
__global__ __launch_bounds__(512) void attn_mfma12(
        const unsigned short* __restrict__ q, const unsigned short* __restrict__ k,
        const unsigned short* __restrict__ v, const unsigned long long* __restrict__ mask,
        unsigned short* __restrict__ ao) {
    __shared__ __align__(16) unsigned short Kb[2][128 * 32];  // K rows, chunk-swizzled
    __shared__ __align__(16) unsigned short Vt[2][32 * VS2];  // V^T [d][sigma128]
    // bijective XCD swizzle (512 % 8 == 0): xcd = flat & 7 gets logical chunk
    int swzb = (blockIdx.x & 7) * 64 + (blockIdx.x >> 3);
    int b = swzb >> 7, h = (swzb >> 4) & 7;
    int q0 = (swzb & 15) * 128;
    int tid = threadIdx.x, w = tid >> 6, lane = tid & 63;
    int lr = lane & 15, lg = lane >> 4;
    size_t bh = (size_t)(b * H_ + h);
    const unsigned short* qbp = q + bh * N_ * HD_;
    const unsigned short* kbp = k + bh * N_ * HD_;
    const unsigned short* vbp = v + bh * N_ * HD_;

    short8 qf = *(const short8*)&qbp[(size_t)(q0 + w * 16 + lr) * HD_ + lg * 8];
    const unsigned long long* mrow = mask + ((size_t)b * N_ + q0 + w * 16 + lr) * (N_ / 64);

    int swz = (lr & 3) ^ ((lr >> 2) & 3);          // K read chunk XOR
    // K staging (waves 0-3): wave w stages rows [w*32, w*32+32) (2 issues)
    int sr = lane >> 2, sc = lane & 3;
    int ssw = (sr & 3) ^ ((sr >> 2) & 3);
    const unsigned short* ksrc = kbp + (size_t)((w & 3) * 32 + sr) * HD_ + (sc ^ ssw) * 8;
    // V staging (waves 4-7): vtid in [0,256): rows {2va,2va+1}, d slice [vd*8,+8)
    int vtid = tid & 255;
    int va = vtid & 63, vd = vtid >> 6;
    const unsigned short* vsrc = vbp + (size_t)(2 * va) * HD_ + vd * 8;
    int p2 = 2 * va;                 // sigma128: keep kc bit, permute within 64
    int sig = (p2 & 64) | (p2 & 35) | ((p2 & 12) << 1) | ((p2 & 16) >> 2);

    short8 ones;
    #pragma unroll
    for (int i = 0; i < 8; i++) ones[i] = (short)0x3F80;   // bf16 1.0

    f32x4 acc0 = {}, acc1 = {}, acc_l = {};
    f32x4 zero = {};
    const int NT = N_ / 128;

    // ---- prologue: stage tile 0 into buffer 0 ----
    if (w < 4) {
        async_copy16(ksrc,            &Kb[0][((w & 3) * 32) * 32]);
        async_copy16(ksrc + 16 * HD_, &Kb[0][((w & 3) * 32 + 16) * 32]);
    } else {
        short8 r0 = *(const short8*)vsrc;
        short8 r1 = *(const short8*)(vsrc + HD_);
        #pragma unroll
        for (int dd = 0; dd < 8; dd++) {
            unsigned pr = ((unsigned)(unsigned short)r1[dd] << 16) | (unsigned short)r0[dd];
            *(unsigned*)&Vt[0][(vd * 8 + dd) * VS2 + sig] = pr;
        }
    }
    unsigned long long mk0c = mrow[0], mk1c = mrow[1];
    unsigned long long mk0n = 0, mk1n = 0;
    short8 r0n = {}, r1n = {};

    for (int t = 0; t < NT; t++) {
        __syncthreads();                        // tile t staged (drains vmcnt+lgkm)
        int cur = t & 1;
        if (t + 1 < NT) {                       // prefetch t+1 (flies under compute)
            size_t koff = (size_t)(t + 1) * 128 * HD_;
            if (w < 4) {
                async_copy16(ksrc + koff,            &Kb[cur ^ 1][((w & 3) * 32) * 32]);
                async_copy16(ksrc + koff + 16 * HD_, &Kb[cur ^ 1][((w & 3) * 32 + 16) * 32]);
            } else {
                r0n = *(const short8*)(vsrc + koff);
                r1n = *(const short8*)(vsrc + koff + HD_);
            }
            mk0n = mrow[2 * (t + 1)];
            mk1n = mrow[2 * (t + 1) + 1];
        }

        // S^T = K @ Q^T : lane (lr=q, lg) gets s for phys k = j*16 + lg*4 + r
        f32x4 s[8];
        __builtin_amdgcn_s_setprio(1);
        #pragma unroll
        for (int j = 0; j < 8; j++) {
            short8 kf = *(const short8*)&Kb[cur][(j * 16 + lr) * 32 + ((lg ^ swz) * 8)];
            s[j] = __builtin_amdgcn_mfma_f32_16x16x32_bf16(kf, qf, zero, 0, 0, 0);
        }
        __builtin_amdgcn_s_setprio(0);

        // max-free masked softmax numerator: select to -200 then raw v_exp (-> +0)
        unsigned mlo0 = (unsigned)(mk0c >> (lg * 4));
        unsigned mhi0 = (unsigned)(mk0c >> (lg * 4 + 32));
        unsigned mlo1 = (unsigned)(mk1c >> (lg * 4));
        unsigned mhi1 = (unsigned)(mk1c >> (lg * 4 + 32));
        #pragma unroll
        for (int j = 0; j < 8; j++) {
            int jj = j & 3;
            unsigned mw = (j < 4) ? ((jj & 2) ? mhi0 : mlo0)
                                  : ((jj & 2) ? mhi1 : mlo1);
            #pragma unroll
            for (int r = 0; r < 4; r++) {
                float sv = ((mw >> ((jj & 1) * 16 + r)) & 1) ? s[j][r] : -200.f;
                s[j][r] = fexp2(sv);
            }
        }

        // P is already the PV A-fragment (key-permuted V): pack in-register
        union u8 { short8 v8; unsigned u[4]; };
        u8 pf[4];
        #pragma unroll
        for (int kc = 0; kc < 4; kc++) {
            pf[kc].u[0] = pk_bf16(s[2 * kc][0], s[2 * kc][1]);
            pf[kc].u[1] = pk_bf16(s[2 * kc][2], s[2 * kc][3]);
            pf[kc].u[2] = pk_bf16(s[2 * kc + 1][0], s[2 * kc + 1][1]);
            pf[kc].u[3] = pk_bf16(s[2 * kc + 1][2], s[2 * kc + 1][3]);
        }

        __builtin_amdgcn_s_setprio(1);
        #pragma unroll
        for (int kc = 0; kc < 4; kc++) {
            short8 vfA = *(const short8*)&Vt[cur][lr * VS2 + kc * 32 + lg * 8];
            short8 vfB = *(const short8*)&Vt[cur][(lr + 16) * VS2 + kc * 32 + lg * 8];
            acc0  = __builtin_amdgcn_mfma_f32_16x16x32_bf16(pf[kc].v8, vfA, acc0, 0, 0, 0);
            acc1  = __builtin_amdgcn_mfma_f32_16x16x32_bf16(pf[kc].v8, vfB, acc1, 0, 0, 0);
            acc_l = __builtin_amdgcn_mfma_f32_16x16x32_bf16(pf[kc].v8, ones, acc_l, 0, 0, 0);
        }
        __builtin_amdgcn_s_setprio(0);

        if (w >= 4 && t + 1 < NT) {             // late V write (loads landed under compute)
            #pragma unroll
            for (int dd = 0; dd < 8; dd++) {
                unsigned pr = ((unsigned)(unsigned short)r1n[dd] << 16) | (unsigned short)r0n[dd];
                *(unsigned*)&Vt[cur ^ 1][(vd * 8 + dd) * VS2 + sig] = pr;
            }
        }
        mk0c = mk0n; mk1c = mk1n;
    }

    // acc_l[r] = l for q-row lg*4+r: already in output fragment layout
    #pragma unroll
    for (int r = 0; r < 4; r++) {
        float lv = acc_l[r];
        float ir = (lv > 0.f) ? frcp(lv) : 0.f;
        int row = q0 + w * 16 + lg * 4 + r;
        unsigned short* op = ao + ((size_t)(b * N_) + row) * D_ + h * HD_;
        op[lr]      = f2bf(acc0[r] * ir);
        op[lr + 16] = f2bf(acc1[r] * ir);
    }
}

// ---------------- Launch -----------------------------------------------------
extern "C" void kernel_launch(void* const* d_in, const int* in_sizes, int n_in,
                              void* d_out, int out_size, void* d_ws, size_t ws_size,
                              hipStream_t stream) {
    const float* x   = (const float*)d_in[0];
    const int*   adj = (const int*)d_in[1];
    const float* wq  = (const float*)d_in[2];
    const float* bq  = (const float*)d_in[3];
    const float* wk  = (const float*)d_in[4];
    const float* bk  = (const float*)d_in[5];
    const float* wv  = (const float*)d_in[6];
    const float* bv  = (const float*)d_in[7];
    const float* wo  = (const float*)d_in[8];
    const float* bo  = (const float*)d_in[9];
    const float* g1  = (const float*)d_in[10];
    const float* be1 = (const float*)d_in[11];
    const float* g2  = (const float*)d_in[12];
    const float* be2 = (const float*)d_in[13];
    const float* w1  = (const float*)d_in[14];
    const float* b1  = (const float*)d_in[15];
    const float* w2  = (const float*)d_in[16];
    const float* b2  = (const float*)d_in[17];
    float* out = (float*)d_out;
    char* base = (char*)d_ws;

    const size_t MB = (size_t)1 << 20;
    unsigned long long* mask = (unsigned long long*)(base);     // 2 MB
    unsigned short* xn     = (unsigned short*)(base + 2*MB);    // 4 MB
    unsigned short* qb     = (unsigned short*)(base + 6*MB);    // 4 MB
    unsigned short* kb     = (unsigned short*)(base + 10*MB);   // 4 MB
    unsigned short* vb     = (unsigned short*)(base + 14*MB);   // 4 MB
    unsigned short* ao     = (unsigned short*)(base + 18*MB);   // 4 MB
    unsigned short* x2bf   = (unsigned short*)(base + 22*MB);   // 4 MB (bf16 x2)
    unsigned short* xbf    = (unsigned short*)(base + 26*MB);   // 4 MB (bf16 x)
    unsigned short* hn     = (unsigned short*)(base + 30*MB);   // 4 MB
    unsigned short* h1     = (unsigned short*)(base + 34*MB);   // 16 MB (FFN)
    unsigned short* wqkvt  = (unsigned short*)(base + 51*MB);   // 384 KB
    unsigned short* wot    = (unsigned short*)(base + 51*MB + 394240);   // 128 KB
    unsigned short* w1t    = (unsigned short*)(base + 52*MB);   // 512 KB
    unsigned short* w2t    = (unsigned short*)(base + 52*MB + 524288);   // 512 KB

    prep_kernel<<<768 + 2048, 256, 0, stream>>>(
        wq, wk, wv, wo, w1, w2, wqkvt, wot, w1t, w2t, x, g1, be1, xn, xbf);
    qkv_pack_kernel<<<768 + 4096, 256, 0, stream>>>(
        xn, wqkvt, bq, bk, bv, qb, kb, vb, adj, (unsigned short*)mask);
    attn_mfma12<<<512, 512, 0, stream>>>(qb, kb, vb, mask, ao);
    gemm_mfma<1, 2, 2><<<dim3(4, 128), 256, 0, stream>>>(
        ao, wot, bo, xbf, x2bf, M_, 256, 256);
    ln_bf_kernel<<<M_ / 4, 256, 0, stream>>>(x2bf, g2, be2, hn);
    gemm_mfma<2, 2, 2><<<dim3(16, 128), 256, 0, stream>>>(
        hn, w1t, b1, nullptr, h1, M_, 1024, 256);
    gemm_mfma<3, 2, 2><<<dim3(4, 128), 256, 0, stream>>>(
        h1, w2t, b2, x2bf, out, M_, 256, 1024);
}

// Round 23
// 108.863 us; speedup vs baseline: 1.1107x; 1.0206x over previous
//
#include <hip/hip_runtime.h>
#include <hip/hip_bf16.h>
#include <math.h>

#define B_ 4
#define N_ 2048
#define D_ 256
#define H_ 8
#define HD_ 32
#define F_ 1024
#define M_ (B_*N_)
#define EPS_ 1e-5f
#define VS2 136

typedef __attribute__((ext_vector_type(8))) short short8;
typedef __attribute__((ext_vector_type(4))) float f32x4;

// log2(e)/sqrt(32): folded into Q so softmax uses exp2 directly
#define QSC 0.2550565499f

#if __has_builtin(__builtin_amdgcn_exp2f)
__device__ inline float fexp2(float x) { return __builtin_amdgcn_exp2f(x); }
#else
__device__ inline float fexp2(float x) { float r; asm("v_exp_f32 %0, %1" : "=v"(r) : "v"(x)); return r; }
#endif
#if __has_builtin(__builtin_amdgcn_rcpf)
__device__ inline float frcp(float x) { return __builtin_amdgcn_rcpf(x); }
#else
__device__ inline float frcp(float x) { float r; asm("v_rcp_f32 %0, %1" : "=v"(r) : "v"(x)); return r; }
#endif

__device__ inline unsigned short f2bf(float f) {
    union { float f; unsigned u; } x; x.f = f;
    unsigned r = x.u + 0x7fff + ((x.u >> 16) & 1);
    return (unsigned short)(r >> 16);
}

__device__ inline float bf2f(unsigned short u) {
    union { unsigned u; float f; } c; c.u = (unsigned)u << 16;
    return c.f;
}

__device__ inline unsigned pk_bf16(float a, float b) {
    union { __hip_bfloat162 h; unsigned u; } c;
    c.h = __float22bfloat162_rn(float2{a, b});
    return c.u;
}

// exact-GELU via Abramowitz-Stegun 7.1.26 erf (|eps| < 1.5e-7), raw v_exp/v_rcp
__device__ inline float gelu_f(float x) {
    float ax = fabsf(x);
    float z = ax * 0.70710678118654752f;
    float t = frcp(fmaf(0.3275911f, z, 1.0f));
    float e = fexp2(-z * z * 1.4426950408889634f);
    float poly = t * fmaf(t, fmaf(t, fmaf(t, fmaf(t, 1.061405429f, -1.453152027f),
                     1.421413741f), -0.284496736f), 0.254829592f);
    float erfv = 1.0f - poly * e;
    float s = (x < 0.f) ? -erfv : erfv;
    return 0.5f * x * (1.0f + s);
}

__device__ inline void async_copy16(const void* g, void* l) {
    __builtin_amdgcn_global_load_lds(
        (const __attribute__((address_space(1))) void*)g,
        (__attribute__((address_space(3))) void*)l, 16, 0, 0);
}

// ---------------- LayerNorm (f32 in): one wave/row; also emits bf16(x) ------
__device__ inline void ln_rows_f32(const float* __restrict__ x,
        const float* __restrict__ g, const float* __restrict__ be,
        unsigned short* __restrict__ out, unsigned short* __restrict__ xbf,
        int blk) {
    int w = threadIdx.x >> 6, lane = threadIdx.x & 63;
    int row = blk * 4 + w;
    float4 v = *(const float4*)&x[(size_t)row * D_ + lane * 4];
    float s  = v.x + v.y + v.z + v.w;
    float s2 = v.x * v.x + v.y * v.y + v.z * v.z + v.w * v.w;
    #pragma unroll
    for (int off = 1; off < 64; off <<= 1) {
        s  += __shfl_xor(s,  off, 64);
        s2 += __shfl_xor(s2, off, 64);
    }
    float mu  = s * (1.0f / D_);
    float var = s2 * (1.0f / D_) - mu * mu;
    float r = rsqrtf(var + EPS_);
    float4 gv = *(const float4*)&g[lane * 4];
    float4 bv = *(const float4*)&be[lane * 4];
    ushort4 u;
    u.x = f2bf((v.x - mu) * r * gv.x + bv.x);
    u.y = f2bf((v.y - mu) * r * gv.y + bv.y);
    u.z = f2bf((v.z - mu) * r * gv.z + bv.z);
    u.w = f2bf((v.w - mu) * r * gv.w + bv.w);
    *(ushort4*)&out[(size_t)row * D_ + lane * 4] = u;
    if (xbf) {
        ushort4 xb;
        xb.x = f2bf(v.x); xb.y = f2bf(v.y); xb.z = f2bf(v.z); xb.w = f2bf(v.w);
        *(ushort4*)&xbf[(size_t)row * D_ + lane * 4] = xb;
    }
}

// ---------------- LayerNorm (bf16 in), bf16 out ------------------------------
__global__ __launch_bounds__(256) void ln_bf_kernel(
        const unsigned short* __restrict__ xb, const float* __restrict__ g,
        const float* __restrict__ be, unsigned short* __restrict__ out) {
    int w = threadIdx.x >> 6, lane = threadIdx.x & 63;
    int row = blockIdx.x * 4 + w;
    ushort4 uv = *(const ushort4*)&xb[(size_t)row * D_ + lane * 4];
    float v0 = bf2f(uv.x), v1 = bf2f(uv.y), v2 = bf2f(uv.z), v3 = bf2f(uv.w);
    float s  = v0 + v1 + v2 + v3;
    float s2 = v0 * v0 + v1 * v1 + v2 * v2 + v3 * v3;
    #pragma unroll
    for (int off = 1; off < 64; off <<= 1) {
        s  += __shfl_xor(s,  off, 64);
        s2 += __shfl_xor(s2, off, 64);
    }
    float mu  = s * (1.0f / D_);
    float var = s2 * (1.0f / D_) - mu * mu;
    float r = rsqrtf(var + EPS_);
    float4 gv = *(const float4*)&g[lane * 4];
    float4 bv = *(const float4*)&be[lane * 4];
    ushort4 u;
    u.x = f2bf((v0 - mu) * r * gv.x + bv.x);
    u.y = f2bf((v1 - mu) * r * gv.y + bv.y);
    u.z = f2bf((v2 - mu) * r * gv.z + bv.z);
    u.w = f2bf((v3 - mu) * r * gv.w + bv.w);
    *(ushort4*)&out[(size_t)row * D_ + lane * 4] = u;
}

// ---------------- prep: weight transpose | LN1 (+bf16 x copy) ----------------
__global__ __launch_bounds__(256) void prep_kernel(
        const float* __restrict__ wq, const float* __restrict__ wk,
        const float* __restrict__ wv, const float* __restrict__ wo,
        const float* __restrict__ w1, const float* __restrict__ w2,
        unsigned short* __restrict__ wqkvt, unsigned short* __restrict__ wot,
        unsigned short* __restrict__ w1t, unsigned short* __restrict__ w2t,
        const float* __restrict__ x, const float* __restrict__ g1,
        const float* __restrict__ be1, unsigned short* __restrict__ xn,
        unsigned short* __restrict__ xbf) {
    __shared__ float t[32][33];
    int id = blockIdx.x;
    if (id >= 768) {
        ln_rows_f32(x, g1, be1, xn, xbf, id - 768);
        return;
    }
    const float* W; unsigned short* Wt; int K, Nc, n0, k0;
    if (id < 256) {
        int m = id >> 6, l = id & 63;
        K = 256; Nc = 256; n0 = (l & 7) * 32; k0 = (l >> 3) * 32;
        W  = m == 0 ? wq : (m == 1 ? wk : (m == 2 ? wv : wo));
        Wt = m == 0 ? wqkvt : (m == 1 ? wqkvt + 65536 : (m == 2 ? wqkvt + 131072 : wot));
    } else if (id < 512) {
        int l = id - 256; K = 256; Nc = 1024; n0 = (l & 31) * 32; k0 = (l >> 5) * 32;
        W = w1; Wt = w1t;
    } else {
        int l = id - 512; K = 1024; Nc = 256; n0 = (l & 7) * 32; k0 = (l >> 3) * 32;
        W = w2; Wt = w2t;
    }
    int tx = threadIdx.x & 31, ty = threadIdx.x >> 5;   // 32 x 8
    #pragma unroll
    for (int i = 0; i < 4; i++)
        t[ty + i * 8][tx] = W[(size_t)(k0 + ty + i * 8) * Nc + n0 + tx];
    __syncthreads();
    #pragma unroll
    for (int i = 0; i < 4; i++)
        Wt[(size_t)(n0 + ty + i * 8) * K + k0 + tx] = f2bf(t[tx][ty + i * 8]);
}

// ---------------- fused QKV GEMM + adj bit-packing ---------------------------
__global__ __launch_bounds__(256) void qkv_pack_kernel(
        const unsigned short* __restrict__ A,
        const unsigned short* __restrict__ Bt,
        const float* __restrict__ bq, const float* __restrict__ bk,
        const float* __restrict__ bv,
        unsigned short* __restrict__ q_out, unsigned short* __restrict__ k_out,
        unsigned short* __restrict__ v_out,
        const int* __restrict__ adj, unsigned short* __restrict__ mask16) {
    constexpr int MI = 4, NI = 2, BM = 128, BN = 64, K = 256, Nc = 768;
    __shared__ __align__(16) unsigned short Abuf[2][BM * 32];
    __shared__ __align__(16) unsigned short Bbuf[2][BN * 32];
    int bid = blockIdx.x;
    if (bid >= 768) {
        int g = (bid - 768) * 256 + threadIdx.x;   // u16 chunk index
        const int4* ap = (const int4*)adj + (size_t)g * 4;
        unsigned bits = 0;
        #pragma unroll
        for (int i = 0; i < 4; i++) {
            int4 v = ap[i];
            bits |= (v.x != 0 ? 1u : 0u) << (4 * i + 0);
            bits |= (v.y != 0 ? 1u : 0u) << (4 * i + 1);
            bits |= (v.z != 0 ? 1u : 0u) << (4 * i + 2);
            bits |= (v.w != 0 ? 1u : 0u) << (4 * i + 3);
        }
        mask16[g] = (unsigned short)bits;
        return;
    }
    int bx = bid % 12, by = bid / 12;
    int tid = threadIdx.x, w = tid >> 6, lane = tid & 63;
    int lr = lane & 15, lg = lane >> 4;
    int wy = w >> 1, wx = w & 1;
    int m0 = by * BM, n0 = bx * BN;
    f32x4 acc[MI][NI] = {};

    int srow = lane >> 2;
    int schunk = lane & 3;

    auto STAGE = [&](int k0, int bi) {
        #pragma unroll
        for (int i = 0; i < BM / 64; i++) {
            int ar = i * 64 + w * 16 + srow;
            int ac = schunk ^ ((ar >> 1) & 3);
            async_copy16(A + (size_t)(m0 + ar) * K + k0 + ac * 8,
                         &Abuf[bi][(i * 64 + w * 16) * 32]);
        }
        #pragma unroll
        for (int i = 0; i < BN / 64; i++) {
            int br = i * 64 + w * 16 + srow;
            int bc = schunk ^ ((br >> 1) & 3);
            async_copy16(Bt + (size_t)(n0 + br) * K + k0 + bc * 8,
                         &Bbuf[bi][(i * 64 + w * 16) * 32]);
        }
    };

    int nkt = K / 32;
    STAGE(0, 0);
    for (int kt = 0; kt < nkt; kt++) {
        __syncthreads();
        int cur = kt & 1;
        if (kt + 1 < nkt) STAGE((kt + 1) * 32, cur ^ 1);

        short8 af[MI], bf[NI];
        #pragma unroll
        for (int mi = 0; mi < MI; mi++) {
            int r = wy * (MI * 16) + mi * 16 + lr;
            int c = lg ^ ((r >> 1) & 3);
            af[mi] = *(const short8*)&Abuf[cur][r * 32 + c * 8];
        }
        #pragma unroll
        for (int ni = 0; ni < NI; ni++) {
            int r = wx * (NI * 16) + ni * 16 + lr;
            int c = lg ^ ((r >> 1) & 3);
            bf[ni] = *(const short8*)&Bbuf[cur][r * 32 + c * 8];
        }
        __builtin_amdgcn_s_setprio(1);
        #pragma unroll
        for (int mi = 0; mi < MI; mi++)
            #pragma unroll
            for (int ni = 0; ni < NI; ni++)
                acc[mi][ni] = __builtin_amdgcn_mfma_f32_16x16x32_bf16(
                        af[mi], bf[ni], acc[mi][ni], 0, 0, 0);
        __builtin_amdgcn_s_setprio(0);
    }

    #pragma unroll
    for (int mi = 0; mi < MI; mi++) {
        #pragma unroll
        for (int r = 0; r < 4; r++) {
            int grow = m0 + wy * (MI * 16) + mi * 16 + lg * 4 + r;
            #pragma unroll
            for (int ni = 0; ni < NI; ni++) {
                int gcol = n0 + wx * (NI * 16) + ni * 16 + lr;
                int which = gcol >> 8, nn = gcol & 255;
                const float* bp = which == 0 ? bq : (which == 1 ? bk : bv);
                float val = acc[mi][ni][r] + bp[nn];
                if (which == 0) val *= QSC;   // fold log2e/sqrt(HD) into Q
                unsigned short* dst = which == 0 ? q_out : (which == 1 ? k_out : v_out);
                int bb = grow >> 11, rr = grow & (N_ - 1);
                int hh = nn >> 5, dd = nn & 31;
                dst[((((size_t)bb * H_ + hh) * N_) + rr) * HD_ + dd] = f2bf(val);
            }
        }
    }
}

// ---------------- bf16 MFMA GEMM, BK=32, double-buffered ---------------------
// MODE 1: bf16 res, bf16 out (O-proj).  MODE 2: gelu, bf16 out (FFN1).
template<int MODE, int MI, int NI>
__global__ __launch_bounds__(256) void gemm_mfma(
        const unsigned short* __restrict__ A,
        const unsigned short* __restrict__ Bt,
        const float* __restrict__ bias, const unsigned short* __restrict__ res,
        void* __restrict__ Cout, int M, int Nc, int K) {
    constexpr int BM = MI * 32, BN = NI * 32;
    __shared__ __align__(16) unsigned short Abuf[2][BM * 32];
    __shared__ __align__(16) unsigned short Bbuf[2][BN * 32];
    int tid = threadIdx.x, w = tid >> 6, lane = tid & 63;
    int lr = lane & 15, lg = lane >> 4;
    int wy = w >> 1, wx = w & 1;
    int m0 = blockIdx.y * BM, n0 = blockIdx.x * BN;
    f32x4 acc[MI][NI] = {};

    int srow = lane >> 2;
    int schunk = lane & 3;

    auto STAGE = [&](int k0, int bi) {
        #pragma unroll
        for (int i = 0; i < BM / 64; i++) {
            int ar = i * 64 + w * 16 + srow;
            int ac = schunk ^ ((ar >> 1) & 3);
            async_copy16(A + (size_t)(m0 + ar) * K + k0 + ac * 8,
                         &Abuf[bi][(i * 64 + w * 16) * 32]);
        }
        #pragma unroll
        for (int i = 0; i < BN / 64; i++) {
            int br = i * 64 + w * 16 + srow;
            int bc = schunk ^ ((br >> 1) & 3);
            async_copy16(Bt + (size_t)(n0 + br) * K + k0 + bc * 8,
                         &Bbuf[bi][(i * 64 + w * 16) * 32]);
        }
    };

    int nkt = K / 32;
    STAGE(0, 0);
    for (int kt = 0; kt < nkt; kt++) {
        __syncthreads();
        int cur = kt & 1;
        if (kt + 1 < nkt) STAGE((kt + 1) * 32, cur ^ 1);

        short8 af[MI], bf[NI];
        #pragma unroll
        for (int mi = 0; mi < MI; mi++) {
            int r = wy * (MI * 16) + mi * 16 + lr;
            int c = lg ^ ((r >> 1) & 3);
            af[mi] = *(const short8*)&Abuf[cur][r * 32 + c * 8];
        }
        #pragma unroll
        for (int ni = 0; ni < NI; ni++) {
            int r = wx * (NI * 16) + ni * 16 + lr;
            int c = lg ^ ((r >> 1) & 3);
            bf[ni] = *(const short8*)&Bbuf[cur][r * 32 + c * 8];
        }
        __builtin_amdgcn_s_setprio(1);
        #pragma unroll
        for (int mi = 0; mi < MI; mi++)
            #pragma unroll
            for (int ni = 0; ni < NI; ni++)
                acc[mi][ni] = __builtin_amdgcn_mfma_f32_16x16x32_bf16(
                        af[mi], bf[ni], acc[mi][ni], 0, 0, 0);
        __builtin_amdgcn_s_setprio(0);
    }

    #pragma unroll
    for (int mi = 0; mi < MI; mi++) {
        #pragma unroll
        for (int r = 0; r < 4; r++) {
            int grow = m0 + wy * (MI * 16) + mi * 16 + lg * 4 + r;
            #pragma unroll
            for (int ni = 0; ni < NI; ni++) {
                int gcol = n0 + wx * (NI * 16) + ni * 16 + lr;
                float val = acc[mi][ni][r] + bias[gcol];
                if (MODE == 2) {
                    val = gelu_f(val);
                    ((unsigned short*)Cout)[(size_t)grow * Nc + gcol] = f2bf(val);
                } else {
                    val += bf2f(res[(size_t)grow * Nc + gcol]);
                    if (MODE == 1)
                        ((unsigned short*)Cout)[(size_t)grow * Nc + gcol] = f2bf(val);
                    else
                        ((float*)Cout)[(size_t)grow * Nc + gcol] = val;
                }
            }
        }
    }
}

// ---------------- FFN2 GEMM: BK=64, 64x64 tile, f32 out + bf16 res -----------
// LDS[r][c] = global[r][c ^ (r&7)]; read chunk g at c = g ^ (r&7).
// FIXED: global_load_lds dest is wave-uniform base + lane*16B -> base must
// include the wave's row offset (w*8 rows of 64 u16).
__global__ __launch_bounds__(256) void gemm_ffn2(
        const unsigned short* __restrict__ A,
        const unsigned short* __restrict__ Bt,
        const float* __restrict__ bias, const unsigned short* __restrict__ res,
        float* __restrict__ Cout, int M, int Nc, int K) {
    constexpr int BM = 64, BN = 64, BK = 64;
    __shared__ __align__(16) unsigned short Abuf[2][BM * BK];
    __shared__ __align__(16) unsigned short Bbuf[2][BN * BK];
    int tid = threadIdx.x, w = tid >> 6, lane = tid & 63;
    int lr = lane & 15, lg = lane >> 4;
    int wy = w >> 1, wx = w & 1;
    int m0 = blockIdx.y * BM, n0 = blockIdx.x * BN;
    f32x4 acc[2][2] = {};

    int srow = tid >> 3;          // 0..31: row within a 32-row issue
    int schunk = tid & 7;         // 0..7 16B chunks per 64-wide row
    int ssw = schunk ^ (srow & 7);

    auto STAGE = [&](int k0, int bi) {
        #pragma unroll
        for (int i = 0; i < 2; i++) {
            async_copy16(A + (size_t)(m0 + i * 32 + srow) * K + k0 + ssw * 8,
                         &Abuf[bi][(i * 32 + w * 8) * BK]);
            async_copy16(Bt + (size_t)(n0 + i * 32 + srow) * K + k0 + ssw * 8,
                         &Bbuf[bi][(i * 32 + w * 8) * BK]);
        }
    };

    int nkt = K / BK;
    STAGE(0, 0);
    for (int kt = 0; kt < nkt; kt++) {
        __syncthreads();
        int cur = kt & 1;
        if (kt + 1 < nkt) STAGE((kt + 1) * BK, cur ^ 1);

        #pragma unroll
        for (int s = 0; s < 2; s++) {         // two K=32 substeps
            short8 af[2], bf[2];
            #pragma unroll
            for (int mi = 0; mi < 2; mi++) {
                int r = wy * 32 + mi * 16 + lr;
                int c = (s * 4 + lg) ^ (r & 7);
                af[mi] = *(const short8*)&Abuf[cur][r * BK + c * 8];
            }
            #pragma unroll
            for (int ni = 0; ni < 2; ni++) {
                int r = wx * 32 + ni * 16 + lr;
                int c = (s * 4 + lg) ^ (r & 7);
                bf[ni] = *(const short8*)&Bbuf[cur][r * BK + c * 8];
            }
            __builtin_amdgcn_s_setprio(1);
            #pragma unroll
            for (int mi = 0; mi < 2; mi++)
                #pragma unroll
                for (int ni = 0; ni < 2; ni++)
                    acc[mi][ni] = __builtin_amdgcn_mfma_f32_16x16x32_bf16(
                            af[mi], bf[ni], acc[mi][ni], 0, 0, 0);
            __builtin_amdgcn_s_setprio(0);
        }
    }

    #pragma unroll
    for (int mi = 0; mi < 2; mi++) {
        #pragma unroll
        for (int r = 0; r < 4; r++) {
            int grow = m0 + wy * 32 + mi * 16 + lg * 4 + r;
            #pragma unroll
            for (int ni = 0; ni < 2; ni++) {
                int gcol = n0 + wx * 32 + ni * 16 + lr;
                float val = acc[mi][ni][r] + bias[gcol]
                          + bf2f(res[(size_t)grow * Nc + gcol]);
                Cout[(size_t)grow * Nc + gcol] = val;
            }
        }
    }
}

// ---------------- MFMA flash attention: 8 waves, KVBLK=128 + XCD swizzle -----
__global__ __launch_bounds__(512) void attn_mfma12(
        const unsigned short* __restrict__ q, const unsigned short* __restrict__ k,
        const unsigned short* __restrict__ v, const unsigned long long* __restrict__ mask,
        unsigned short* __restrict__ ao) {
    __shared__ __align__(16) unsigned short Kb[2][128 * 32];  // K rows, chunk-swizzled
    __shared__ __align__(16) unsigned short Vt[2][32 * VS2];  // V^T [d][sigma128]
    // bijective XCD swizzle (512 % 8 == 0): xcd = flat & 7 gets logical chunk
    int swzb = (blockIdx.x & 7) * 64 + (blockIdx.x >> 3);
    int b = swzb >> 7, h = (swzb >> 4) & 7;
    int q0 = (swzb & 15) * 128;
    int tid = threadIdx.x, w = tid >> 6, lane = tid & 63;
    int lr = lane & 15, lg = lane >> 4;
    size_t bh = (size_t)(b * H_ + h);
    const unsigned short* qbp = q + bh * N_ * HD_;
    const unsigned short* kbp = k + bh * N_ * HD_;
    const unsigned short* vbp = v + bh * N_ * HD_;

    short8 qf = *(const short8*)&qbp[(size_t)(q0 + w * 16 + lr) * HD_ + lg * 8];
    const unsigned long long* mrow = mask + ((size_t)b * N_ + q0 + w * 16 + lr) * (N_ / 64);

    int swz = (lr & 3) ^ ((lr >> 2) & 3);          // K read chunk XOR
    // K staging (waves 0-3): wave w stages rows [w*32, w*32+32) (2 issues)
    int sr = lane >> 2, sc = lane & 3;
    int ssw = (sr & 3) ^ ((sr >> 2) & 3);
    const unsigned short* ksrc = kbp + (size_t)((w & 3) * 32 + sr) * HD_ + (sc ^ ssw) * 8;
    // V staging (waves 4-7): vtid in [0,256): rows {2va,2va+1}, d slice [vd*8,+8)
    int vtid = tid & 255;
    int va = vtid & 63, vd = vtid >> 6;
    const unsigned short* vsrc = vbp + (size_t)(2 * va) * HD_ + vd * 8;
    int p2 = 2 * va;                 // sigma128: keep kc bit, permute within 64
    int sig = (p2 & 64) | (p2 & 35) | ((p2 & 12) << 1) | ((p2 & 16) >> 2);

    short8 ones;
    #pragma unroll
    for (int i = 0; i < 8; i++) ones[i] = (short)0x3F80;   // bf16 1.0

    f32x4 acc0 = {}, acc1 = {}, acc_l = {};
    f32x4 zero = {};
    const int NT = N_ / 128;

    // ---- prologue: stage tile 0 into buffer 0 ----
    if (w < 4) {
        async_copy16(ksrc,            &Kb[0][((w & 3) * 32) * 32]);
        async_copy16(ksrc + 16 * HD_, &Kb[0][((w & 3) * 32 + 16) * 32]);
    } else {
        short8 r0 = *(const short8*)vsrc;
        short8 r1 = *(const short8*)(vsrc + HD_);
        #pragma unroll
        for (int dd = 0; dd < 8; dd++) {
            unsigned pr = ((unsigned)(unsigned short)r1[dd] << 16) | (unsigned short)r0[dd];
            *(unsigned*)&Vt[0][(vd * 8 + dd) * VS2 + sig] = pr;
        }
    }
    unsigned long long mk0c = mrow[0], mk1c = mrow[1];
    unsigned long long mk0n = 0, mk1n = 0;
    short8 r0n = {}, r1n = {};

    for (int t = 0; t < NT; t++) {
        __syncthreads();                        // tile t staged (drains vmcnt+lgkm)
        int cur = t & 1;
        if (t + 1 < NT) {                       // prefetch t+1 (flies under compute)
            size_t koff = (size_t)(t + 1) * 128 * HD_;
            if (w < 4) {
                async_copy16(ksrc + koff,            &Kb[cur ^ 1][((w & 3) * 32) * 32]);
                async_copy16(ksrc + koff + 16 * HD_, &Kb[cur ^ 1][((w & 3) * 32 + 16) * 32]);
            } else {
                r0n = *(const short8*)(vsrc + koff);
                r1n = *(const short8*)(vsrc + koff + HD_);
            }
            mk0n = mrow[2 * (t + 1)];
            mk1n = mrow[2 * (t + 1) + 1];
        }

        // S^T = K @ Q^T : lane (lr=q, lg) gets s for phys k = j*16 + lg*4 + r
        f32x4 s[8];
        __builtin_amdgcn_s_setprio(1);
        #pragma unroll
        for (int j = 0; j < 8; j++) {
            short8 kf = *(const short8*)&Kb[cur][(j * 16 + lr) * 32 + ((lg ^ swz) * 8)];
            s[j] = __builtin_amdgcn_mfma_f32_16x16x32_bf16(kf, qf, zero, 0, 0, 0);
        }
        __builtin_amdgcn_s_setprio(0);

        // max-free masked softmax numerator: select to -200 then raw v_exp (-> +0)
        unsigned mlo0 = (unsigned)(mk0c >> (lg * 4));
        unsigned mhi0 = (unsigned)(mk0c >> (lg * 4 + 32));
        unsigned mlo1 = (unsigned)(mk1c >> (lg * 4));
        unsigned mhi1 = (unsigned)(mk1c >> (lg * 4 + 32));
        #pragma unroll
        for (int j = 0; j < 8; j++) {
            int jj = j & 3;
            unsigned mw = (j < 4) ? ((jj & 2) ? mhi0 : mlo0)
                                  : ((jj & 2) ? mhi1 : mlo1);
            #pragma unroll
            for (int r = 0; r < 4; r++) {
                float sv = ((mw >> ((jj & 1) * 16 + r)) & 1) ? s[j][r] : -200.f;
                s[j][r] = fexp2(sv);
            }
        }

        // P is already the PV A-fragment (key-permuted V): pack in-register
        union u8 { short8 v8; unsigned u[4]; };
        u8 pf[4];
        #pragma unroll
        for (int kc = 0; kc < 4; kc++) {
            pf[kc].u[0] = pk_bf16(s[2 * kc][0], s[2 * kc][1]);
            pf[kc].u[1] = pk_bf16(s[2 * kc][2], s[2 * kc][3]);
            pf[kc].u[2] = pk_bf16(s[2 * kc + 1][0], s[2 * kc + 1][1]);
            pf[kc].u[3] = pk_bf16(s[2 * kc + 1][2], s[2 * kc + 1][3]);
        }

        __builtin_amdgcn_s_setprio(1);
        #pragma unroll
        for (int kc = 0; kc < 4; kc++) {
            short8 vfA = *(const short8*)&Vt[cur][lr * VS2 + kc * 32 + lg * 8];
            short8 vfB = *(const short8*)&Vt[cur][(lr + 16) * VS2 + kc * 32 + lg * 8];
            acc0  = __builtin_amdgcn_mfma_f32_16x16x32_bf16(pf[kc].v8, vfA, acc0, 0, 0, 0);
            acc1  = __builtin_amdgcn_mfma_f32_16x16x32_bf16(pf[kc].v8, vfB, acc1, 0, 0, 0);
            acc_l = __builtin_amdgcn_mfma_f32_16x16x32_bf16(pf[kc].v8, ones, acc_l, 0, 0, 0);
        }
        __builtin_amdgcn_s_setprio(0);

        if (w >= 4 && t + 1 < NT) {             // late V write (loads landed under compute)
            #pragma unroll
            for (int dd = 0; dd < 8; dd++) {
                unsigned pr = ((unsigned)(unsigned short)r1n[dd] << 16) | (unsigned short)r0n[dd];
                *(unsigned*)&Vt[cur ^ 1][(vd * 8 + dd) * VS2 + sig] = pr;
            }
        }
        mk0c = mk0n; mk1c = mk1n;
    }

    // acc_l[r] = l for q-row lg*4+r: already in output fragment layout
    #pragma unroll
    for (int r = 0; r < 4; r++) {
        float lv = acc_l[r];
        float ir = (lv > 0.f) ? frcp(lv) : 0.f;
        int row = q0 + w * 16 + lg * 4 + r;
        unsigned short* op = ao + ((size_t)(b * N_) + row) * D_ + h * HD_;
        op[lr]      = f2bf(acc0[r] * ir);
        op[lr + 16] = f2bf(acc1[r] * ir);
    }
}

// ---------------- Launch -----------------------------------------------------
extern "C" void kernel_launch(void* const* d_in, const int* in_sizes, int n_in,
                              void* d_out, int out_size, void* d_ws, size_t ws_size,
                              hipStream_t stream) {
    const float* x   = (const float*)d_in[0];
    const int*   adj = (const int*)d_in[1];
    const float* wq  = (const float*)d_in[2];
    const float* bq  = (const float*)d_in[3];
    const float* wk  = (const float*)d_in[4];
    const float* bk  = (const float*)d_in[5];
    const float* wv  = (const float*)d_in[6];
    const float* bv  = (const float*)d_in[7];
    const float* wo  = (const float*)d_in[8];
    const float* bo  = (const float*)d_in[9];
    const float* g1  = (const float*)d_in[10];
    const float* be1 = (const float*)d_in[11];
    const float* g2  = (const float*)d_in[12];
    const float* be2 = (const float*)d_in[13];
    const float* w1  = (const float*)d_in[14];
    const float* b1  = (const float*)d_in[15];
    const float* w2  = (const float*)d_in[16];
    const float* b2  = (const float*)d_in[17];
    float* out = (float*)d_out;
    char* base = (char*)d_ws;

    const size_t MB = (size_t)1 << 20;
    unsigned long long* mask = (unsigned long long*)(base);     // 2 MB
    unsigned short* xn     = (unsigned short*)(base + 2*MB);    // 4 MB
    unsigned short* qb     = (unsigned short*)(base + 6*MB);    // 4 MB
    unsigned short* kb     = (unsigned short*)(base + 10*MB);   // 4 MB
    unsigned short* vb     = (unsigned short*)(base + 14*MB);   // 4 MB
    unsigned short* ao     = (unsigned short*)(base + 18*MB);   // 4 MB
    unsigned short* x2bf   = (unsigned short*)(base + 22*MB);   // 4 MB (bf16 x2)
    unsigned short* xbf    = (unsigned short*)(base + 26*MB);   // 4 MB (bf16 x)
    unsigned short* hn     = (unsigned short*)(base + 30*MB);   // 4 MB
    unsigned short* h1     = (unsigned short*)(base + 34*MB);   // 16 MB (FFN)
    unsigned short* wqkvt  = (unsigned short*)(base + 51*MB);   // 384 KB
    unsigned short* wot    = (unsigned short*)(base + 51*MB + 394240);   // 128 KB
    unsigned short* w1t    = (unsigned short*)(base + 52*MB);   // 512 KB
    unsigned short* w2t    = (unsigned short*)(base + 52*MB + 524288);   // 512 KB

    prep_kernel<<<768 + 2048, 256, 0, stream>>>(
        wq, wk, wv, wo, w1, w2, wqkvt, wot, w1t, w2t, x, g1, be1, xn, xbf);
    qkv_pack_kernel<<<768 + 4096, 256, 0, stream>>>(
        xn, wqkvt, bq, bk, bv, qb, kb, vb, adj, (unsigned short*)mask);
    attn_mfma12<<<512, 512, 0, stream>>>(qb, kb, vb, mask, ao);
    gemm_mfma<1, 2, 2><<<dim3(4, 128), 256, 0, stream>>>(
        ao, wot, bo, xbf, x2bf, M_, 256, 256);
    ln_bf_kernel<<<M_ / 4, 256, 0, stream>>>(x2bf, g2, be2, hn);
    gemm_mfma<2, 2, 2><<<dim3(16, 128), 256, 0, stream>>>(
        hn, w1t, b1, nullptr, h1, M_, 1024, 256);
    gemm_ffn2<<<dim3(4, 128), 256, 0, stream>>>(
        h1, w2t, b2, x2bf, out, M_, 256, 1024);
}

// Round 24
// 107.121 us; speedup vs baseline: 1.1287x; 1.0163x over previous
//
#include <hip/hip_runtime.h>
#include <hip/hip_bf16.h>
#include <math.h>

#define B_ 4
#define N_ 2048
#define D_ 256
#define H_ 8
#define HD_ 32
#define F_ 1024
#define M_ (B_*N_)
#define EPS_ 1e-5f
#define VS2 136

typedef __attribute__((ext_vector_type(8))) short short8;
typedef __attribute__((ext_vector_type(4))) float f32x4;

// log2(e)/sqrt(32): folded into Q so softmax uses exp2 directly
#define QSC 0.2550565499f

#if __has_builtin(__builtin_amdgcn_exp2f)
__device__ inline float fexp2(float x) { return __builtin_amdgcn_exp2f(x); }
#else
__device__ inline float fexp2(float x) { float r; asm("v_exp_f32 %0, %1" : "=v"(r) : "v"(x)); return r; }
#endif
#if __has_builtin(__builtin_amdgcn_rcpf)
__device__ inline float frcp(float x) { return __builtin_amdgcn_rcpf(x); }
#else
__device__ inline float frcp(float x) { float r; asm("v_rcp_f32 %0, %1" : "=v"(r) : "v"(x)); return r; }
#endif

__device__ inline unsigned short f2bf(float f) {
    union { float f; unsigned u; } x; x.f = f;
    unsigned r = x.u + 0x7fff + ((x.u >> 16) & 1);
    return (unsigned short)(r >> 16);
}

__device__ inline float bf2f(unsigned short u) {
    union { unsigned u; float f; } c; c.u = (unsigned)u << 16;
    return c.f;
}

__device__ inline unsigned pk_bf16(float a, float b) {
    union { __hip_bfloat162 h; unsigned u; } c;
    c.h = __float22bfloat162_rn(float2{a, b});
    return c.u;
}

// exact-GELU via Abramowitz-Stegun 7.1.26 erf (|eps| < 1.5e-7), raw v_exp/v_rcp
__device__ inline float gelu_f(float x) {
    float ax = fabsf(x);
    float z = ax * 0.70710678118654752f;
    float t = frcp(fmaf(0.3275911f, z, 1.0f));
    float e = fexp2(-z * z * 1.4426950408889634f);
    float poly = t * fmaf(t, fmaf(t, fmaf(t, fmaf(t, 1.061405429f, -1.453152027f),
                     1.421413741f), -0.284496736f), 0.254829592f);
    float erfv = 1.0f - poly * e;
    float s = (x < 0.f) ? -erfv : erfv;
    return 0.5f * x * (1.0f + s);
}

__device__ inline void async_copy16(const void* g, void* l) {
    __builtin_amdgcn_global_load_lds(
        (const __attribute__((address_space(1))) void*)g,
        (__attribute__((address_space(3))) void*)l, 16, 0, 0);
}

// ---------------- LayerNorm (f32 in): one wave/row; also emits bf16(x) ------
__device__ inline void ln_rows_f32(const float* __restrict__ x,
        const float* __restrict__ g, const float* __restrict__ be,
        unsigned short* __restrict__ out, unsigned short* __restrict__ xbf,
        int blk) {
    int w = threadIdx.x >> 6, lane = threadIdx.x & 63;
    int row = blk * 4 + w;
    float4 v = *(const float4*)&x[(size_t)row * D_ + lane * 4];
    float s  = v.x + v.y + v.z + v.w;
    float s2 = v.x * v.x + v.y * v.y + v.z * v.z + v.w * v.w;
    #pragma unroll
    for (int off = 1; off < 64; off <<= 1) {
        s  += __shfl_xor(s,  off, 64);
        s2 += __shfl_xor(s2, off, 64);
    }
    float mu  = s * (1.0f / D_);
    float var = s2 * (1.0f / D_) - mu * mu;
    float r = rsqrtf(var + EPS_);
    float4 gv = *(const float4*)&g[lane * 4];
    float4 bv = *(const float4*)&be[lane * 4];
    ushort4 u;
    u.x = f2bf((v.x - mu) * r * gv.x + bv.x);
    u.y = f2bf((v.y - mu) * r * gv.y + bv.y);
    u.z = f2bf((v.z - mu) * r * gv.z + bv.z);
    u.w = f2bf((v.w - mu) * r * gv.w + bv.w);
    *(ushort4*)&out[(size_t)row * D_ + lane * 4] = u;
    if (xbf) {
        ushort4 xb;
        xb.x = f2bf(v.x); xb.y = f2bf(v.y); xb.z = f2bf(v.z); xb.w = f2bf(v.w);
        *(ushort4*)&xbf[(size_t)row * D_ + lane * 4] = xb;
    }
}

// ---------------- LayerNorm (bf16 in), bf16 out ------------------------------
__global__ __launch_bounds__(256) void ln_bf_kernel(
        const unsigned short* __restrict__ xb, const float* __restrict__ g,
        const float* __restrict__ be, unsigned short* __restrict__ out) {
    int w = threadIdx.x >> 6, lane = threadIdx.x & 63;
    int row = blockIdx.x * 4 + w;
    ushort4 uv = *(const ushort4*)&xb[(size_t)row * D_ + lane * 4];
    float v0 = bf2f(uv.x), v1 = bf2f(uv.y), v2 = bf2f(uv.z), v3 = bf2f(uv.w);
    float s  = v0 + v1 + v2 + v3;
    float s2 = v0 * v0 + v1 * v1 + v2 * v2 + v3 * v3;
    #pragma unroll
    for (int off = 1; off < 64; off <<= 1) {
        s  += __shfl_xor(s,  off, 64);
        s2 += __shfl_xor(s2, off, 64);
    }
    float mu  = s * (1.0f / D_);
    float var = s2 * (1.0f / D_) - mu * mu;
    float r = rsqrtf(var + EPS_);
    float4 gv = *(const float4*)&g[lane * 4];
    float4 bv = *(const float4*)&be[lane * 4];
    ushort4 u;
    u.x = f2bf((v0 - mu) * r * gv.x + bv.x);
    u.y = f2bf((v1 - mu) * r * gv.y + bv.y);
    u.z = f2bf((v2 - mu) * r * gv.z + bv.z);
    u.w = f2bf((v3 - mu) * r * gv.w + bv.w);
    *(ushort4*)&out[(size_t)row * D_ + lane * 4] = u;
}

// ---------------- prep: weight transpose | LN1 (+bf16 x copy) ----------------
__global__ __launch_bounds__(256) void prep_kernel(
        const float* __restrict__ wq, const float* __restrict__ wk,
        const float* __restrict__ wv, const float* __restrict__ wo,
        const float* __restrict__ w1, const float* __restrict__ w2,
        unsigned short* __restrict__ wqkvt, unsigned short* __restrict__ wot,
        unsigned short* __restrict__ w1t, unsigned short* __restrict__ w2t,
        const float* __restrict__ x, const float* __restrict__ g1,
        const float* __restrict__ be1, unsigned short* __restrict__ xn,
        unsigned short* __restrict__ xbf) {
    __shared__ float t[32][33];
    int id = blockIdx.x;
    if (id >= 768) {
        ln_rows_f32(x, g1, be1, xn, xbf, id - 768);
        return;
    }
    const float* W; unsigned short* Wt; int K, Nc, n0, k0;
    if (id < 256) {
        int m = id >> 6, l = id & 63;
        K = 256; Nc = 256; n0 = (l & 7) * 32; k0 = (l >> 3) * 32;
        W  = m == 0 ? wq : (m == 1 ? wk : (m == 2 ? wv : wo));
        Wt = m == 0 ? wqkvt : (m == 1 ? wqkvt + 65536 : (m == 2 ? wqkvt + 131072 : wot));
    } else if (id < 512) {
        int l = id - 256; K = 256; Nc = 1024; n0 = (l & 31) * 32; k0 = (l >> 5) * 32;
        W = w1; Wt = w1t;
    } else {
        int l = id - 512; K = 1024; Nc = 256; n0 = (l & 7) * 32; k0 = (l >> 3) * 32;
        W = w2; Wt = w2t;
    }
    int tx = threadIdx.x & 31, ty = threadIdx.x >> 5;   // 32 x 8
    #pragma unroll
    for (int i = 0; i < 4; i++)
        t[ty + i * 8][tx] = W[(size_t)(k0 + ty + i * 8) * Nc + n0 + tx];
    __syncthreads();
    #pragma unroll
    for (int i = 0; i < 4; i++)
        Wt[(size_t)(n0 + ty + i * 8) * K + k0 + tx] = f2bf(t[tx][ty + i * 8]);
}

// ---------------- fused QKV GEMM + adj bit-packing ---------------------------
__global__ __launch_bounds__(256) void qkv_pack_kernel(
        const unsigned short* __restrict__ A,
        const unsigned short* __restrict__ Bt,
        const float* __restrict__ bq, const float* __restrict__ bk,
        const float* __restrict__ bv,
        unsigned short* __restrict__ q_out, unsigned short* __restrict__ k_out,
        unsigned short* __restrict__ v_out,
        const int* __restrict__ adj, unsigned short* __restrict__ mask16) {
    constexpr int MI = 4, NI = 2, BM = 128, BN = 64, K = 256, Nc = 768;
    __shared__ __align__(16) unsigned short Abuf[2][BM * 32];
    __shared__ __align__(16) unsigned short Bbuf[2][BN * 32];
    int bid = blockIdx.x;
    if (bid >= 768) {
        int g = (bid - 768) * 256 + threadIdx.x;   // u16 chunk index
        const int4* ap = (const int4*)adj + (size_t)g * 4;
        unsigned bits = 0;
        #pragma unroll
        for (int i = 0; i < 4; i++) {
            int4 v = ap[i];
            bits |= (v.x != 0 ? 1u : 0u) << (4 * i + 0);
            bits |= (v.y != 0 ? 1u : 0u) << (4 * i + 1);
            bits |= (v.z != 0 ? 1u : 0u) << (4 * i + 2);
            bits |= (v.w != 0 ? 1u : 0u) << (4 * i + 3);
        }
        mask16[g] = (unsigned short)bits;
        return;
    }
    int bx = bid % 12, by = bid / 12;
    int tid = threadIdx.x, w = tid >> 6, lane = tid & 63;
    int lr = lane & 15, lg = lane >> 4;
    int wy = w >> 1, wx = w & 1;
    int m0 = by * BM, n0 = bx * BN;
    f32x4 acc[MI][NI] = {};

    int srow = lane >> 2;
    int schunk = lane & 3;

    auto STAGE = [&](int k0, int bi) {
        #pragma unroll
        for (int i = 0; i < BM / 64; i++) {
            int ar = i * 64 + w * 16 + srow;
            int ac = schunk ^ ((ar >> 1) & 3);
            async_copy16(A + (size_t)(m0 + ar) * K + k0 + ac * 8,
                         &Abuf[bi][(i * 64 + w * 16) * 32]);
        }
        #pragma unroll
        for (int i = 0; i < BN / 64; i++) {
            int br = i * 64 + w * 16 + srow;
            int bc = schunk ^ ((br >> 1) & 3);
            async_copy16(Bt + (size_t)(n0 + br) * K + k0 + bc * 8,
                         &Bbuf[bi][(i * 64 + w * 16) * 32]);
        }
    };

    int nkt = K / 32;
    STAGE(0, 0);
    for (int kt = 0; kt < nkt; kt++) {
        __syncthreads();
        int cur = kt & 1;
        if (kt + 1 < nkt) STAGE((kt + 1) * 32, cur ^ 1);

        short8 af[MI], bf[NI];
        #pragma unroll
        for (int mi = 0; mi < MI; mi++) {
            int r = wy * (MI * 16) + mi * 16 + lr;
            int c = lg ^ ((r >> 1) & 3);
            af[mi] = *(const short8*)&Abuf[cur][r * 32 + c * 8];
        }
        #pragma unroll
        for (int ni = 0; ni < NI; ni++) {
            int r = wx * (NI * 16) + ni * 16 + lr;
            int c = lg ^ ((r >> 1) & 3);
            bf[ni] = *(const short8*)&Bbuf[cur][r * 32 + c * 8];
        }
        __builtin_amdgcn_s_setprio(1);
        #pragma unroll
        for (int mi = 0; mi < MI; mi++)
            #pragma unroll
            for (int ni = 0; ni < NI; ni++)
                acc[mi][ni] = __builtin_amdgcn_mfma_f32_16x16x32_bf16(
                        af[mi], bf[ni], acc[mi][ni], 0, 0, 0);
        __builtin_amdgcn_s_setprio(0);
    }

    #pragma unroll
    for (int mi = 0; mi < MI; mi++) {
        #pragma unroll
        for (int r = 0; r < 4; r++) {
            int grow = m0 + wy * (MI * 16) + mi * 16 + lg * 4 + r;
            #pragma unroll
            for (int ni = 0; ni < NI; ni++) {
                int gcol = n0 + wx * (NI * 16) + ni * 16 + lr;
                int which = gcol >> 8, nn = gcol & 255;
                const float* bp = which == 0 ? bq : (which == 1 ? bk : bv);
                float val = acc[mi][ni][r] + bp[nn];
                if (which == 0) val *= QSC;   // fold log2e/sqrt(HD) into Q
                unsigned short* dst = which == 0 ? q_out : (which == 1 ? k_out : v_out);
                int bb = grow >> 11, rr = grow & (N_ - 1);
                int hh = nn >> 5, dd = nn & 31;
                dst[((((size_t)bb * H_ + hh) * N_) + rr) * HD_ + dd] = f2bf(val);
            }
        }
    }
}

// ---------------- BK=64 64x64 GEMM (proven in R23's FFN2) --------------------
// MODE 1: bf16 res, bf16 out (O-proj).  MODE 2: gelu, bf16 out (FFN1).
// MODE 3: bf16 res, f32 out (FFN2 -> final output).
// LDS[r][c] = global[r][c ^ (r&7)]; read chunk g at c = g ^ (r&7).
// global_load_lds dest base includes the wave's row offset (w*8 rows).
template<int MODE>
__global__ __launch_bounds__(256) void gemm_bk64(
        const unsigned short* __restrict__ A,
        const unsigned short* __restrict__ Bt,
        const float* __restrict__ bias, const unsigned short* __restrict__ res,
        void* __restrict__ Cout, int M, int Nc, int K) {
    constexpr int BM = 64, BN = 64, BK = 64;
    __shared__ __align__(16) unsigned short Abuf[2][BM * BK];
    __shared__ __align__(16) unsigned short Bbuf[2][BN * BK];
    int tid = threadIdx.x, w = tid >> 6, lane = tid & 63;
    int lr = lane & 15, lg = lane >> 4;
    int wy = w >> 1, wx = w & 1;
    int m0 = blockIdx.y * BM, n0 = blockIdx.x * BN;
    f32x4 acc[2][2] = {};

    int srow = tid >> 3;          // 0..31: row within a 32-row issue
    int schunk = tid & 7;         // 0..7 16B chunks per 64-wide row
    int ssw = schunk ^ (srow & 7);

    auto STAGE = [&](int k0, int bi) {
        #pragma unroll
        for (int i = 0; i < 2; i++) {
            async_copy16(A + (size_t)(m0 + i * 32 + srow) * K + k0 + ssw * 8,
                         &Abuf[bi][(i * 32 + w * 8) * BK]);
            async_copy16(Bt + (size_t)(n0 + i * 32 + srow) * K + k0 + ssw * 8,
                         &Bbuf[bi][(i * 32 + w * 8) * BK]);
        }
    };

    int nkt = K / BK;
    STAGE(0, 0);
    for (int kt = 0; kt < nkt; kt++) {
        __syncthreads();
        int cur = kt & 1;
        if (kt + 1 < nkt) STAGE((kt + 1) * BK, cur ^ 1);

        #pragma unroll
        for (int s = 0; s < 2; s++) {         // two K=32 substeps
            short8 af[2], bf[2];
            #pragma unroll
            for (int mi = 0; mi < 2; mi++) {
                int r = wy * 32 + mi * 16 + lr;
                int c = (s * 4 + lg) ^ (r & 7);
                af[mi] = *(const short8*)&Abuf[cur][r * BK + c * 8];
            }
            #pragma unroll
            for (int ni = 0; ni < 2; ni++) {
                int r = wx * 32 + ni * 16 + lr;
                int c = (s * 4 + lg) ^ (r & 7);
                bf[ni] = *(const short8*)&Bbuf[cur][r * BK + c * 8];
            }
            __builtin_amdgcn_s_setprio(1);
            #pragma unroll
            for (int mi = 0; mi < 2; mi++)
                #pragma unroll
                for (int ni = 0; ni < 2; ni++)
                    acc[mi][ni] = __builtin_amdgcn_mfma_f32_16x16x32_bf16(
                            af[mi], bf[ni], acc[mi][ni], 0, 0, 0);
            __builtin_amdgcn_s_setprio(0);
        }
    }

    #pragma unroll
    for (int mi = 0; mi < 2; mi++) {
        #pragma unroll
        for (int r = 0; r < 4; r++) {
            int grow = m0 + wy * 32 + mi * 16 + lg * 4 + r;
            #pragma unroll
            for (int ni = 0; ni < 2; ni++) {
                int gcol = n0 + wx * 32 + ni * 16 + lr;
                float val = acc[mi][ni][r] + bias[gcol];
                if (MODE == 2) {
                    val = gelu_f(val);
                    ((unsigned short*)Cout)[(size_t)grow * Nc + gcol] = f2bf(val);
                } else {
                    val += bf2f(res[(size_t)grow * Nc + gcol]);
                    if (MODE == 1)
                        ((unsigned short*)Cout)[(size_t)grow * Nc + gcol] = f2bf(val);
                    else
                        ((float*)Cout)[(size_t)grow * Nc + gcol] = val;
                }
            }
        }
    }
}

// ---------------- MFMA flash attention: 8 waves, KVBLK=128 + XCD swizzle -----
__global__ __launch_bounds__(512) void attn_mfma12(
        const unsigned short* __restrict__ q, const unsigned short* __restrict__ k,
        const unsigned short* __restrict__ v, const unsigned long long* __restrict__ mask,
        unsigned short* __restrict__ ao) {
    __shared__ __align__(16) unsigned short Kb[2][128 * 32];  // K rows, chunk-swizzled
    __shared__ __align__(16) unsigned short Vt[2][32 * VS2];  // V^T [d][sigma128]
    // bijective XCD swizzle (512 % 8 == 0): xcd = flat & 7 gets logical chunk
    int swzb = (blockIdx.x & 7) * 64 + (blockIdx.x >> 3);
    int b = swzb >> 7, h = (swzb >> 4) & 7;
    int q0 = (swzb & 15) * 128;
    int tid = threadIdx.x, w = tid >> 6, lane = tid & 63;
    int lr = lane & 15, lg = lane >> 4;
    size_t bh = (size_t)(b * H_ + h);
    const unsigned short* qbp = q + bh * N_ * HD_;
    const unsigned short* kbp = k + bh * N_ * HD_;
    const unsigned short* vbp = v + bh * N_ * HD_;

    short8 qf = *(const short8*)&qbp[(size_t)(q0 + w * 16 + lr) * HD_ + lg * 8];
    const unsigned long long* mrow = mask + ((size_t)b * N_ + q0 + w * 16 + lr) * (N_ / 64);

    int swz = (lr & 3) ^ ((lr >> 2) & 3);          // K read chunk XOR
    // K staging (waves 0-3): wave w stages rows [w*32, w*32+32) (2 issues)
    int sr = lane >> 2, sc = lane & 3;
    int ssw = (sr & 3) ^ ((sr >> 2) & 3);
    const unsigned short* ksrc = kbp + (size_t)((w & 3) * 32 + sr) * HD_ + (sc ^ ssw) * 8;
    // V staging (waves 4-7): vtid in [0,256): rows {2va,2va+1}, d slice [vd*8,+8)
    int vtid = tid & 255;
    int va = vtid & 63, vd = vtid >> 6;
    const unsigned short* vsrc = vbp + (size_t)(2 * va) * HD_ + vd * 8;
    int p2 = 2 * va;                 // sigma128: keep kc bit, permute within 64
    int sig = (p2 & 64) | (p2 & 35) | ((p2 & 12) << 1) | ((p2 & 16) >> 2);

    short8 ones;
    #pragma unroll
    for (int i = 0; i < 8; i++) ones[i] = (short)0x3F80;   // bf16 1.0

    f32x4 acc0 = {}, acc1 = {}, acc_l = {};
    f32x4 zero = {};
    const int NT = N_ / 128;

    // ---- prologue: stage tile 0 into buffer 0 ----
    if (w < 4) {
        async_copy16(ksrc,            &Kb[0][((w & 3) * 32) * 32]);
        async_copy16(ksrc + 16 * HD_, &Kb[0][((w & 3) * 32 + 16) * 32]);
    } else {
        short8 r0 = *(const short8*)vsrc;
        short8 r1 = *(const short8*)(vsrc + HD_);
        #pragma unroll
        for (int dd = 0; dd < 8; dd++) {
            unsigned pr = ((unsigned)(unsigned short)r1[dd] << 16) | (unsigned short)r0[dd];
            *(unsigned*)&Vt[0][(vd * 8 + dd) * VS2 + sig] = pr;
        }
    }
    unsigned long long mk0c = mrow[0], mk1c = mrow[1];
    unsigned long long mk0n = 0, mk1n = 0;
    short8 r0n = {}, r1n = {};

    for (int t = 0; t < NT; t++) {
        __syncthreads();                        // tile t staged (drains vmcnt+lgkm)
        int cur = t & 1;
        if (t + 1 < NT) {                       // prefetch t+1 (flies under compute)
            size_t koff = (size_t)(t + 1) * 128 * HD_;
            if (w < 4) {
                async_copy16(ksrc + koff,            &Kb[cur ^ 1][((w & 3) * 32) * 32]);
                async_copy16(ksrc + koff + 16 * HD_, &Kb[cur ^ 1][((w & 3) * 32 + 16) * 32]);
            } else {
                r0n = *(const short8*)(vsrc + koff);
                r1n = *(const short8*)(vsrc + koff + HD_);
            }
            mk0n = mrow[2 * (t + 1)];
            mk1n = mrow[2 * (t + 1) + 1];
        }

        // S^T = K @ Q^T : lane (lr=q, lg) gets s for phys k = j*16 + lg*4 + r
        f32x4 s[8];
        __builtin_amdgcn_s_setprio(1);
        #pragma unroll
        for (int j = 0; j < 8; j++) {
            short8 kf = *(const short8*)&Kb[cur][(j * 16 + lr) * 32 + ((lg ^ swz) * 8)];
            s[j] = __builtin_amdgcn_mfma_f32_16x16x32_bf16(kf, qf, zero, 0, 0, 0);
        }
        __builtin_amdgcn_s_setprio(0);

        // max-free masked softmax numerator: select to -200 then raw v_exp (-> +0)
        unsigned mlo0 = (unsigned)(mk0c >> (lg * 4));
        unsigned mhi0 = (unsigned)(mk0c >> (lg * 4 + 32));
        unsigned mlo1 = (unsigned)(mk1c >> (lg * 4));
        unsigned mhi1 = (unsigned)(mk1c >> (lg * 4 + 32));
        #pragma unroll
        for (int j = 0; j < 8; j++) {
            int jj = j & 3;
            unsigned mw = (j < 4) ? ((jj & 2) ? mhi0 : mlo0)
                                  : ((jj & 2) ? mhi1 : mlo1);
            #pragma unroll
            for (int r = 0; r < 4; r++) {
                float sv = ((mw >> ((jj & 1) * 16 + r)) & 1) ? s[j][r] : -200.f;
                s[j][r] = fexp2(sv);
            }
        }

        // P is already the PV A-fragment (key-permuted V): pack in-register
        union u8 { short8 v8; unsigned u[4]; };
        u8 pf[4];
        #pragma unroll
        for (int kc = 0; kc < 4; kc++) {
            pf[kc].u[0] = pk_bf16(s[2 * kc][0], s[2 * kc][1]);
            pf[kc].u[1] = pk_bf16(s[2 * kc][2], s[2 * kc][3]);
            pf[kc].u[2] = pk_bf16(s[2 * kc + 1][0], s[2 * kc + 1][1]);
            pf[kc].u[3] = pk_bf16(s[2 * kc + 1][2], s[2 * kc + 1][3]);
        }

        __builtin_amdgcn_s_setprio(1);
        #pragma unroll
        for (int kc = 0; kc < 4; kc++) {
            short8 vfA = *(const short8*)&Vt[cur][lr * VS2 + kc * 32 + lg * 8];
            short8 vfB = *(const short8*)&Vt[cur][(lr + 16) * VS2 + kc * 32 + lg * 8];
            acc0  = __builtin_amdgcn_mfma_f32_16x16x32_bf16(pf[kc].v8, vfA, acc0, 0, 0, 0);
            acc1  = __builtin_amdgcn_mfma_f32_16x16x32_bf16(pf[kc].v8, vfB, acc1, 0, 0, 0);
            acc_l = __builtin_amdgcn_mfma_f32_16x16x32_bf16(pf[kc].v8, ones, acc_l, 0, 0, 0);
        }
        __builtin_amdgcn_s_setprio(0);

        if (w >= 4 && t + 1 < NT) {             // late V write (loads landed under compute)
            #pragma unroll
            for (int dd = 0; dd < 8; dd++) {
                unsigned pr = ((unsigned)(unsigned short)r1n[dd] << 16) | (unsigned short)r0n[dd];
                *(unsigned*)&Vt[cur ^ 1][(vd * 8 + dd) * VS2 + sig] = pr;
            }
        }
        mk0c = mk0n; mk1c = mk1n;
    }

    // acc_l[r] = l for q-row lg*4+r: already in output fragment layout
    #pragma unroll
    for (int r = 0; r < 4; r++) {
        float lv = acc_l[r];
        float ir = (lv > 0.f) ? frcp(lv) : 0.f;
        int row = q0 + w * 16 + lg * 4 + r;
        unsigned short* op = ao + ((size_t)(b * N_) + row) * D_ + h * HD_;
        op[lr]      = f2bf(acc0[r] * ir);
        op[lr + 16] = f2bf(acc1[r] * ir);
    }
}

// ---------------- Launch -----------------------------------------------------
extern "C" void kernel_launch(void* const* d_in, const int* in_sizes, int n_in,
                              void* d_out, int out_size, void* d_ws, size_t ws_size,
                              hipStream_t stream) {
    const float* x   = (const float*)d_in[0];
    const int*   adj = (const int*)d_in[1];
    const float* wq  = (const float*)d_in[2];
    const float* bq  = (const float*)d_in[3];
    const float* wk  = (const float*)d_in[4];
    const float* bk  = (const float*)d_in[5];
    const float* wv  = (const float*)d_in[6];
    const float* bv  = (const float*)d_in[7];
    const float* wo  = (const float*)d_in[8];
    const float* bo  = (const float*)d_in[9];
    const float* g1  = (const float*)d_in[10];
    const float* be1 = (const float*)d_in[11];
    const float* g2  = (const float*)d_in[12];
    const float* be2 = (const float*)d_in[13];
    const float* w1  = (const float*)d_in[14];
    const float* b1  = (const float*)d_in[15];
    const float* w2  = (const float*)d_in[16];
    const float* b2  = (const float*)d_in[17];
    float* out = (float*)d_out;
    char* base = (char*)d_ws;

    const size_t MB = (size_t)1 << 20;
    unsigned long long* mask = (unsigned long long*)(base);     // 2 MB
    unsigned short* xn     = (unsigned short*)(base + 2*MB);    // 4 MB
    unsigned short* qb     = (unsigned short*)(base + 6*MB);    // 4 MB
    unsigned short* kb     = (unsigned short*)(base + 10*MB);   // 4 MB
    unsigned short* vb     = (unsigned short*)(base + 14*MB);   // 4 MB
    unsigned short* ao     = (unsigned short*)(base + 18*MB);   // 4 MB
    unsigned short* x2bf   = (unsigned short*)(base + 22*MB);   // 4 MB (bf16 x2)
    unsigned short* xbf    = (unsigned short*)(base + 26*MB);   // 4 MB (bf16 x)
    unsigned short* hn     = (unsigned short*)(base + 30*MB);   // 4 MB
    unsigned short* h1     = (unsigned short*)(base + 34*MB);   // 16 MB (FFN)
    unsigned short* wqkvt  = (unsigned short*)(base + 51*MB);   // 384 KB
    unsigned short* wot    = (unsigned short*)(base + 51*MB + 394240);   // 128 KB
    unsigned short* w1t    = (unsigned short*)(base + 52*MB);   // 512 KB
    unsigned short* w2t    = (unsigned short*)(base + 52*MB + 524288);   // 512 KB

    prep_kernel<<<768 + 2048, 256, 0, stream>>>(
        wq, wk, wv, wo, w1, w2, wqkvt, wot, w1t, w2t, x, g1, be1, xn, xbf);
    qkv_pack_kernel<<<768 + 4096, 256, 0, stream>>>(
        xn, wqkvt, bq, bk, bv, qb, kb, vb, adj, (unsigned short*)mask);
    attn_mfma12<<<512, 512, 0, stream>>>(qb, kb, vb, mask, ao);
    gemm_bk64<1><<<dim3(4, 128), 256, 0, stream>>>(
        ao, wot, bo, xbf, x2bf, M_, 256, 256);
    ln_bf_kernel<<<M_ / 4, 256, 0, stream>>>(x2bf, g2, be2, hn);
    gemm_bk64<2><<<dim3(16, 128), 256, 0, stream>>>(
        hn, w1t, b1, nullptr, h1, M_, 1024, 256);
    gemm_bk64<3><<<dim3(4, 128), 256, 0, stream>>>(
        h1, w2t, b2, x2bf, out, M_, 256, 1024);
}